// Round 15
// baseline (4810.996 us; speedup 1.0000x reference)
//
#include <hip/hip_runtime.h>
#include <hip/hip_bf16.h>

typedef __bf16 bf16;
typedef __bf16 bf16x8 __attribute__((ext_vector_type(8)));
typedef float f32x4 __attribute__((ext_vector_type(4)));

#define N_ROWS   512      // rows 0..255 seq1, 256..511 seq2
#define HID      1024
#define KX       320      // EMB=300 padded to 320
#define KTOT     1344     // 320 + 1024
#define NSTEPS   128
#define EMB_D    300
#define HC_W     3332     // 1025+1025+1+1025+256

// workspace layout (bytes)
#define WBT_OFF   0UL          // bf16 [4096][1344]  (packed p2 order, transposed)
#define XB_OFF    11010048UL   // bf16 [128][512][320]
#define HB_OFF    52953088UL   // bf16 [2][512][1024]
#define BIASP_OFF 55050240UL   // f32  [4096] (packed p2 order)
#define HC_OFF    55066624UL   // f32  [256][3332]
#define H2T_OFF   58478592UL   // f32  [1025][256]
#define T1_OFF    59528192UL   // f32  [256][1025]
#define E1_OFF    60577792UL   // f32  [256][512]
// barrier region (dwords from BAR_OFF):
//   ga[g]   at dword g*16   (g=0..15)  16 monotonic arrive lines, 64B apart
//   gsum    at dword 512               monotonic summary line
//   flag[t] at dword 768 + t*16        per-step flag lines (fresh each step)
#define BAR_OFF   61102080UL

// ENVELOPE RULE (14 rounds of evidence): cooperative kernel: 256-thread
// blocks, __launch_bounds__(256,2), compiled VGPR <= 128, static LDS small
// enough for the declared occupancy. No multi-slot register staging arrays
// (r7/r8/r11: compiler remat -> 7x L2-fill blowup).
// r15: grid 512 (2 blocks/CU co-resident) for TLP — at grid 256 the
// kernel ran 1 block/CU (Occupancy 12.4%) and ALL latency was exposed.

__device__ __forceinline__ float sigm(float x) { return 1.f / (1.f + __expf(-x)); }
__device__ __forceinline__ float tanh_fast(float x) {
  float xc = fminf(fmaxf(x, -15.f), 15.f);
  float e = __expf(2.f * xc);
  return (e - 1.f) / (e + 1.f);
}

// LDS-only barrier (r14): does not drain vmcnt.
__device__ __forceinline__ void lds_barrier() {
  asm volatile("s_waitcnt lgkmcnt(0)" ::: "memory");
  __builtin_amdgcn_sched_barrier(0);
  __builtin_amdgcn_s_barrier();
  __builtin_amdgcn_sched_barrier(0);
}

// ---- pack kernels -------------------------------------------------------
// packed order: p2 = cb*64 + g*16 + c  <->  orig col g*1024 + cb*16 + c
__global__ void pack_wbt(const float* __restrict__ lk, bf16* __restrict__ wbt) {
  int p = blockIdx.x * 256 + threadIdx.x;   // 0..4095
  int k = blockIdx.y;                        // 0..1343
  int cb = p >> 6, g = (p >> 4) & 3, c = p & 15;
  int oc = g * HID + cb * 16 + c;
  float v = 0.f;
  if (k < KX) { if (k < EMB_D) v = lk[(size_t)k * 4096 + oc]; }
  else v = lk[(size_t)(EMB_D + k - KX) * 4096 + oc];
  wbt[(size_t)p * KTOT + k] = (bf16)v;
}

// vectorized bf16x8 writes; block 320 = 8 timesteps x 40 e-groups (r11-proven)
__global__ void pack_xb(const int* __restrict__ in1, const int* __restrict__ in2,
                        const float* __restrict__ emb, bf16* __restrict__ xb) {
  int r = blockIdx.x;                        // 0..511
  int t = blockIdx.y * 8 + threadIdx.x / 40; // 0..127
  int e8 = threadIdx.x % 40;                 // 0..39 (8 elems each)
  int tok = (r < 256) ? in1[r * 128 + t] : in2[(r - 256) * 128 + t];
  const float* er = emb + (size_t)tok * EMB_D + e8 * 8;
  bf16x8 v;
  if (e8 < 37) {
#pragma unroll
    for (int i = 0; i < 8; ++i) v[i] = (bf16)er[i];
  } else {
#pragma unroll
    for (int i = 0; i < 8; ++i) {
      int e = e8 * 8 + i;
      v[i] = (e < EMB_D) ? (bf16)er[i] : (bf16)0.f;
    }
  }
  *reinterpret_cast<bf16x8*>(&xb[((size_t)t * N_ROWS + r) * KX + e8 * 8]) = v;
}

__global__ void pack_misc(const float* __restrict__ h1i, const float* __restrict__ h2i,
                          const float* __restrict__ bias, bf16* __restrict__ hb0,
                          float* __restrict__ biasp, unsigned* __restrict__ bar) {
  int idx = blockIdx.x * 256 + threadIdx.x;
  if (idx < N_ROWS * HID) {
    int r = idx >> 10, k = idx & 1023;
    float v = (r < 256) ? h1i[(size_t)r * HID + k] : h2i[(size_t)(r - 256) * HID + k];
    hb0[idx] = (bf16)v;
  }
  if (idx < 4096) {
    int cb = idx >> 6, g = (idx >> 4) & 3, c = idx & 15;
    biasp[idx] = bias[g * HID + cb * 16 + c];
    bar[idx] = 0u;   // reset all barrier lines (16 KB region) every launch
  }
}

// ---- cooperative LSTM recurrence ---------------------------------------
// grid 512 = 8 row-blocks x 64 col-groups; 2 blocks/CU co-resident (TLP!).
// Block: 64 rows x 64 pcols (all 4 gates of 16 cells, p2 packing).
// Wave w owns rows w*16..+15:
//   acc[ni][q] = G[row=w*16+(lane>>4)*4+q][pcol=ni*16+(lane&15)]
//   gate = ni, cell = cb*16 + (lane&15): cell update fully in-register.
// LDS 32 KB (As/Bs each [2][64][64]); staging 4 threads/row, 2 chunks each.
// Barrier: 16 arrive lines x 32 fan-in -> 16-fan summary -> flag[t];
// wait at kc==3 (before first h-load issue at nkc=5). Otherwise r13/r14.
__launch_bounds__(256, 2)
__global__ void lstm_coop(const bf16* __restrict__ xb, const bf16* __restrict__ wbt,
                          bf16* __restrict__ hb, const float* __restrict__ biasp,
                          const float* __restrict__ c1i, const float* __restrict__ c2i,
                          const int* __restrict__ s1, const int* __restrict__ s2,
                          unsigned* __restrict__ bar) {
  __shared__ bf16 As[2][64][64];     // 16 KB, XOR-swizzled 16B chunks
  __shared__ bf16 Bs[2][64][64];     // 16 KB  (total 32 KB)
  const int tid = threadIdx.x;
  const int wave = tid >> 6;
  const int lane = tid & 63;
  const int lrow = lane & 15;
  const int hi = lane >> 4;        // 0..3
  const int l7 = lane & 7;
  const int bid = blockIdx.x;
  const int rb = bid >> 6;         // 0..7
  const int cb = bid & 63;         // 0..63
  const int r0 = rb * 64;

  const int cellabs = cb * 16 + lrow;    // this lane's cell column (orig order)

  int slen[4];        // per q: row = r0 + wave*16 + hi*4 + q
#pragma unroll
  for (int q = 0; q < 4; ++q) {
    int rr = r0 + wave * 16 + hi * 4 + q;
    slen[q] = (rr < 256) ? s1[rr] : s2[rr - 256];
  }

  float creg[4];      // [q] cell state, f32 in registers
#pragma unroll
  for (int q = 0; q < 4; ++q) {
    int rr = r0 + wave * 16 + hi * 4 + q;
    const float* cbp = (rr < 256) ? (c1i + (size_t)rr * HID)
                                  : (c2i + (size_t)(rr - 256) * HID);
    creg[q] = cbp[cellabs];
  }

  // bias folded into accumulator init: acc[ni] col = ni*16+lrow = gate ni
  float bv[4];
#pragma unroll
  for (int ni = 0; ni < 4; ++ni)
    bv[ni] = biasp[cb * 64 + ni * 16 + lrow];

  // staging thread mapping: A/B 64 rows x 8 chunks, 4 threads/row, 2 chunks
  // each. XOR swizzle: chunk cc -> col ((cc ^ (row&7)) << 3).
  const int a_r = tid >> 2, a_cb = (tid & 3) * 2;

  bf16x8 ra[2], rbv2[2];
  auto issue_loads = [&](int nt, int nkc) {
    const bf16* asrc = (nkc < 5)
        ? (xb + ((size_t)nt * N_ROWS + r0 + a_r) * KX + nkc * 64 + a_cb * 8)
        : (hb + ((size_t)(nt & 1) << 19) + ((size_t)(r0 + a_r) << 10) +
           (nkc * 64 - KX) + a_cb * 8);
#pragma unroll
    for (int q = 0; q < 2; ++q)
      ra[q] = *reinterpret_cast<const bf16x8*>(asrc + q * 8);
    const bf16* bsrc = wbt + (size_t)(cb * 64 + a_r) * KTOT + nkc * 64 + a_cb * 8;
#pragma unroll
    for (int q = 0; q < 2; ++q)
      rbv2[q] = *reinterpret_cast<const bf16x8*>(bsrc + q * 8);
  };
  auto stage_to = [&](int buf) {
#pragma unroll
    for (int q = 0; q < 2; ++q)
      *reinterpret_cast<bf16x8*>(&As[buf][a_r][((a_cb + q) ^ (a_r & 7)) << 3]) = ra[q];
#pragma unroll
    for (int q = 0; q < 2; ++q)
      *reinterpret_cast<bf16x8*>(&Bs[buf][a_r][((a_cb + q) ^ (a_r & 7)) << 3]) = rbv2[q];
  };

  // prologue: buf0 <- chunk 0 (t=0, x); regs <- chunk 1
  issue_loads(0, 0);
  stage_to(0);
  issue_loads(0, 1);
  __syncthreads();
  int db = 0;

  unsigned* ga    = bar + (bid & 15) * 16;  // own arrive line (64B apart, 16 lines)
  unsigned* gsum  = bar + 512;              // summary line
  unsigned* flags = bar + 768;              // flag[t] at flags + t*16

  for (int t = 0; t < NSTEPS; ++t) {
    f32x4 acc[4];
#pragma unroll
    for (int ni = 0; ni < 4; ++ni)
      acc[ni] = f32x4{bv[ni], bv[ni], bv[ni], bv[ni]};

    for (int kc = 0; kc < 21; ++kc) {
      // stage chunk kc+1 (regs invariant) into the other buffer
      stage_to(db ^ 1);

      // grid wait: peers' h(t) must be visible before the first h-load ISSUE
      // (nkc=5, issued this iteration). x-chunks 0..2 covered the latency.
      if (kc == 3 && t > 0) {
        if (tid == 0) {
          const unsigned* fl = flags + (t - 1) * 16;
          while (__hip_atomic_load(fl, __ATOMIC_RELAXED, __HIP_MEMORY_SCOPE_AGENT) == 0u)
            __builtin_amdgcn_s_sleep(2);
          (void)__hip_atomic_load(fl, __ATOMIC_ACQUIRE, __HIP_MEMORY_SCOPE_AGENT);
        }
        __syncthreads();
      }

      // issue loads for chunk kc+2 (wraps into next step's x-chunks)
      {
        int nkc = kc + 2, nt = t;
        if (nkc > 20) { nkc -= 21; ++nt; }
        if (nt < NSTEPS) issue_loads(nt, nkc);
      }

      // compute chunk kc from buf[db]: per ks, 1 A-frag + 4 B-frags, 4 MFMAs
#pragma unroll
      for (int ks = 0; ks < 2; ++ks) {
        const int cs = (((ks << 2) | hi) ^ l7) << 3;
        bf16x8 af = *reinterpret_cast<const bf16x8*>(
            &As[db][wave * 16 + lrow][cs]);
#pragma unroll
        for (int ni = 0; ni < 4; ++ni) {
          bf16x8 bfv = *reinterpret_cast<const bf16x8*>(&Bs[db][ni * 16 + lrow][cs]);
          acc[ni] = __builtin_amdgcn_mfma_f32_16x16x32_bf16(af, bfv, acc[ni], 0, 0, 0);
        }
      }
      lds_barrier();   // lgkmcnt-only: prefetch loads stay in flight
      db ^= 1;
    }

    // cell update: lane owns 4 rows x 1 cell, all 4 gates in-register (g=ni)
    {
      const size_t curo = (size_t)(t & 1) << 19;
      const bf16* hc = hb + curo;
      bf16* hnb = hb + (curo ^ ((size_t)1 << 19));
#pragma unroll
      for (int q = 0; q < 4; ++q) {
        float ig = acc[0][q];
        float jg = acc[1][q];
        float fg = acc[2][q];
        float og = acc[3][q];
        float cn = sigm(fg + 1.f) * creg[q] + sigm(ig) * tanh_fast(jg);
        float hv = tanh_fast(cn) * sigm(og);
        int rr = r0 + wave * 16 + hi * 4 + q;
        size_t off = ((size_t)rr << 10) + cellabs;
        float ho;
        if (t < slen[q]) { creg[q] = cn; ho = hv; }
        else ho = (float)hc[off];
        hnb[off] = (bf16)ho;
      }
    }

    // arrive: full __syncthreads (drains h stores) then hierarchical release
    // chain: ga (32 fan-in, 16 lines) -> gsum (16 fan-in) -> flag[t].
    __syncthreads();
    if (t < NSTEPS - 1 && tid == 0) {
      unsigned prev = __hip_atomic_fetch_add(ga, 1u, __ATOMIC_RELEASE,
                                             __HIP_MEMORY_SCOPE_AGENT);
      if ((prev & 31u) == 31u) {        // 32nd arrival of this step on this line
        (void)__hip_atomic_load(ga, __ATOMIC_ACQUIRE, __HIP_MEMORY_SCOPE_AGENT);
        unsigned p2 = __hip_atomic_fetch_add(gsum, 1u, __ATOMIC_RELEASE,
                                             __HIP_MEMORY_SCOPE_AGENT);
        if ((p2 & 15u) == 15u) {        // all 16 groups done
          (void)__hip_atomic_load(gsum, __ATOMIC_ACQUIRE, __HIP_MEMORY_SCOPE_AGENT);
          __hip_atomic_store(flags + t * 16, 1u, __ATOMIC_RELEASE,
                             __HIP_MEMORY_SCOPE_AGENT);
        }
      }
    }
  }
}

// ---- head ---------------------------------------------------------------
__global__ void feat_kernel(const bf16* __restrict__ hb0, const int* __restrict__ s1,
                            const int* __restrict__ s2, float* __restrict__ HC,
                            float* __restrict__ H2T) {
  int a = blockIdx.x;
  int tid = threadIdx.x;
  __shared__ float red[256];
  const bf16* h1r = hb0 + (size_t)a * HID;
  const bf16* h2r = hb0 + (size_t)(a + 256) * HID;
  float l1 = (float)s1[a] * (1.f / 128.f);
  float l2 = (float)s2[a] * (1.f / 128.f);
  float dacc = 0.f;
  for (int k = tid; k < 1025; k += 256) {
    float v1 = (k < HID) ? (float)h1r[k] : l1;
    float v2 = (k < HID) ? (float)h2r[k] : l2;
    HC[(size_t)a * HC_W + k] = v1;
    HC[(size_t)a * HC_W + 1025 + k] = v2;
    HC[(size_t)a * HC_W + 2051 + k] = v1 * v2;
    H2T[(size_t)k * 256 + a] = v2;
    float d = v1 - v2;
    dacc += d * d;
  }
  red[tid] = dacc;
  __syncthreads();
  for (int s = 128; s > 0; s >>= 1) {
    if (tid < s) red[tid] += red[tid + s];
    __syncthreads();
  }
  if (tid == 0) HC[(size_t)a * HC_W + 2050] = red[0];
}

// 8 rows/block (grid 5 x 32) — r11-proven
__global__ void t1_kernel(const float* __restrict__ HC, const float* __restrict__ Wh,
                          float* __restrict__ T1) {
  int j = blockIdx.x * 256 + threadIdx.x;
  int a0 = blockIdx.y * 8;
  __shared__ float sh[8][64];
  float acc[8];
#pragma unroll
  for (int r = 0; r < 8; ++r) acc[r] = 0.f;
  for (int kc = 0; kc < 1025; kc += 64) {
    int kn = (1025 - kc < 64) ? (1025 - kc) : 64;
    for (int idx = threadIdx.x; idx < 512; idx += 256) {
      int r = idx >> 6, kk = idx & 63;
      sh[r][kk] = (kk < kn) ? HC[(size_t)(a0 + r) * HC_W + kc + kk] : 0.f;
    }
    __syncthreads();
    if (j < 1025) {
      for (int kk = 0; kk < kn; ++kk) {
        float w = Wh[(size_t)(kc + kk) * 1025 + j];
#pragma unroll
        for (int r = 0; r < 8; ++r) acc[r] += sh[r][kk] * w;
      }
    }
    __syncthreads();
  }
  if (j < 1025) {
    for (int r = 0; r < 8; ++r) T1[(size_t)(a0 + r) * 1025 + j] = acc[r];
  }
}

__global__ void inter_kernel(const float* __restrict__ T1, const float* __restrict__ H2T,
                             float* __restrict__ HC) {
  int a0 = blockIdx.x * 8;
  int b = threadIdx.x;
  __shared__ float sT[8][1025];
  for (int idx = threadIdx.x; idx < 8 * 1025; idx += 256) {
    int r = idx / 1025, k = idx - r * 1025;
    sT[r][k] = T1[(size_t)(a0 + r) * 1025 + k];
  }
  __syncthreads();
  float acc[8];
#pragma unroll
  for (int r = 0; r < 8; ++r) acc[r] = 0.f;
  for (int k = 0; k < 1025; ++k) {
    float v = H2T[(size_t)k * 256 + b];
#pragma unroll
    for (int r = 0; r < 8; ++r) acc[r] += sT[r][k] * v;
  }
#pragma unroll
  for (int r = 0; r < 8; ++r)
    HC[(size_t)(a0 + r) * HC_W + 3076 + b] = acc[r];
}

__global__ void e1_kernel(const float* __restrict__ HC, const float* __restrict__ W1,
                          const float* __restrict__ b1, float* __restrict__ E1) {
  int a0 = blockIdx.x * 8;
  int j = blockIdx.y * 256 + threadIdx.x;
  __shared__ float sh[8][128];
  float acc[8];
#pragma unroll
  for (int r = 0; r < 8; ++r) acc[r] = 0.f;
  for (int kc = 0; kc < HC_W; kc += 128) {
    int kn = (HC_W - kc < 128) ? (HC_W - kc) : 128;
    for (int idx = threadIdx.x; idx < 1024; idx += 256) {
      int r = idx >> 7, kk = idx & 127;
      sh[r][kk] = (kk < kn) ? HC[(size_t)(a0 + r) * HC_W + kc + kk] : 0.f;
    }
    __syncthreads();
    for (int kk = 0; kk < kn; ++kk) {
      float w = W1[(size_t)(kc + kk) * 512 + j];
#pragma unroll
      for (int r = 0; r < 8; ++r) acc[r] += sh[r][kk] * w;
    }
    __syncthreads();
  }
  float bj = b1[j];
#pragma unroll
  for (int r = 0; r < 8; ++r)
    E1[(size_t)(a0 + r) * 512 + j] = fmaxf(acc[r] + bj, 0.f);
}

__global__ void out_kernel(const float* __restrict__ E1, const float* __restrict__ W2,
                           const float* __restrict__ b2, float* __restrict__ out) {
  int a = threadIdx.x;
  float a0 = 0.f, a1 = 0.f;
  const float* e = E1 + (size_t)a * 512;
  for (int k = 0; k < 512; ++k) {
    float v = e[k];
    a0 += v * W2[2 * k];
    a1 += v * W2[2 * k + 1];
  }
  out[2 * a] = a0 + b2[0];
  out[2 * a + 1] = a1 + b2[1];
}

// ---- host ---------------------------------------------------------------
extern "C" void kernel_launch(void* const* d_in, const int* in_sizes, int n_in,
                              void* d_out, int out_size, void* d_ws, size_t ws_size,
                              hipStream_t stream) {
  const int*   input1 = (const int*)d_in[0];
  const int*   input2 = (const int*)d_in[1];
  const int*   seql1  = (const int*)d_in[2];
  const int*   seql2  = (const int*)d_in[3];
  const float* emb    = (const float*)d_in[4];
  const float* lk     = (const float*)d_in[5];
  const float* lbias  = (const float*)d_in[6];
  const float* c1i    = (const float*)d_in[7];
  const float* h1i    = (const float*)d_in[8];
  const float* c2i    = (const float*)d_in[9];
  const float* h2i    = (const float*)d_in[10];
  const float* W_h    = (const float*)d_in[11];
  const float* W1     = (const float*)d_in[12];
  const float* b1     = (const float*)d_in[13];
  const float* W2     = (const float*)d_in[14];
  const float* b2     = (const float*)d_in[15];

  char* ws = (char*)d_ws;
  bf16*     WbT   = (bf16*)(ws + WBT_OFF);
  bf16*     Xb    = (bf16*)(ws + XB_OFF);
  bf16*     Hb    = (bf16*)(ws + HB_OFF);
  float*    biasp = (float*)(ws + BIASP_OFF);
  float*    HC    = (float*)(ws + HC_OFF);
  float*    H2T   = (float*)(ws + H2T_OFF);
  float*    T1    = (float*)(ws + T1_OFF);
  float*    E1    = (float*)(ws + E1_OFF);
  unsigned* bar   = (unsigned*)(ws + BAR_OFF);

  pack_wbt<<<dim3(16, 1344), 256, 0, stream>>>(lk, WbT);
  pack_xb<<<dim3(512, 16), 320, 0, stream>>>(input1, input2, emb, Xb);
  pack_misc<<<2048, 256, 0, stream>>>(h1i, h2i, lbias, Hb, biasp, bar);

  void* kargs[] = { (void*)&Xb, (void*)&WbT, (void*)&Hb, (void*)&biasp,
                    (void*)&c1i, (void*)&c2i, (void*)&seql1, (void*)&seql2,
                    (void*)&bar };
  hipLaunchCooperativeKernel((void*)lstm_coop, dim3(512), dim3(256), kargs, 0, stream);

  feat_kernel<<<256, 256, 0, stream>>>(Hb, seql1, seql2, HC, H2T);
  t1_kernel<<<dim3(5, 32), 256, 0, stream>>>(HC, W_h, T1);
  inter_kernel<<<32, 256, 0, stream>>>(T1, H2T, HC);
  e1_kernel<<<dim3(32, 2), 256, 0, stream>>>(HC, W1, b1, E1);
  out_kernel<<<1, 256, 0, stream>>>(E1, W2, b2, (float*)d_out);
}

// Round 16
// 4408.299 us; speedup vs baseline: 1.0913x; 1.0913x over previous
//
#include <hip/hip_runtime.h>
#include <hip/hip_bf16.h>

typedef __bf16 bf16;
typedef __bf16 bf16x8 __attribute__((ext_vector_type(8)));
typedef float f32x4 __attribute__((ext_vector_type(4)));

#define N_ROWS   512      // rows 0..255 seq1, 256..511 seq2
#define HID      1024
#define KX       320      // EMB=300 padded to 320
#define KTOT     1344     // 320 + 1024
#define NSTEPS   128
#define EMB_D    300
#define HC_W     3332     // 1025+1025+1+1025+256

// workspace layout (bytes)
#define WBT_OFF   0UL          // bf16 [4096][1344]  (packed p2 order, transposed)
#define XB_OFF    11010048UL   // bf16 [128][512][320]
#define HB_OFF    52953088UL   // bf16 [2][512][1024]
#define BIASP_OFF 55050240UL   // f32  [4096] (packed p2 order)
#define HC_OFF    55066624UL   // f32  [256][3332]
#define H2T_OFF   58478592UL   // f32  [1025][256]
#define T1_OFF    59528192UL   // f32  [256][1025]
#define E1_OFF    60577792UL   // f32  [256][512]
// barrier region (dwords from BAR_OFF):
//   ga[g]   at dword g*16   (g=0..7)   8 monotonic arrive lines, 64B apart
//   gsum    at dword 128               monotonic summary line
//   flag[t] at dword 256 + t*16        per-step flag lines (fresh each step)
#define BAR_OFF   61102080UL

// ENVELOPE RULE (15 rounds): coop kernel = 256-thread blocks, grid 256,
// __launch_bounds__(256,2), VGPR <= 128, LDS <= 49KB. No multi-slot register
// staging arrays (r7/r8/r11 remat blowup). Grid 512 / 2 blocks/CU REGRESSES
// (r15: per-CU LDS traffic doubles; LDS BW is the top cost, ~35% of step).

__device__ __forceinline__ float sigm(float x) { return 1.f / (1.f + __expf(-x)); }
__device__ __forceinline__ float tanh_fast(float x) {
  float xc = fminf(fmaxf(x, -15.f), 15.f);
  float e = __expf(2.f * xc);
  return (e - 1.f) / (e + 1.f);
}

// LDS-only barrier (r14): does not drain vmcnt (prefetches stay in flight).
__device__ __forceinline__ void lds_barrier() {
  asm volatile("s_waitcnt lgkmcnt(0)" ::: "memory");
  __builtin_amdgcn_sched_barrier(0);
  __builtin_amdgcn_s_barrier();
  __builtin_amdgcn_sched_barrier(0);
}

// ---- pack kernels -------------------------------------------------------
// packed order: p2 = cb*64 + g*16 + c  <->  orig col g*1024 + cb*16 + c
__global__ void pack_wbt(const float* __restrict__ lk, bf16* __restrict__ wbt) {
  int p = blockIdx.x * 256 + threadIdx.x;   // 0..4095
  int k = blockIdx.y;                        // 0..1343
  int cb = p >> 6, g = (p >> 4) & 3, c = p & 15;
  int oc = g * HID + cb * 16 + c;
  float v = 0.f;
  if (k < KX) { if (k < EMB_D) v = lk[(size_t)k * 4096 + oc]; }
  else v = lk[(size_t)(EMB_D + k - KX) * 4096 + oc];
  wbt[(size_t)p * KTOT + k] = (bf16)v;
}

// vectorized bf16x8 writes; block 320 = 8 timesteps x 40 e-groups (r11-proven)
__global__ void pack_xb(const int* __restrict__ in1, const int* __restrict__ in2,
                        const float* __restrict__ emb, bf16* __restrict__ xb) {
  int r = blockIdx.x;                        // 0..511
  int t = blockIdx.y * 8 + threadIdx.x / 40; // 0..127
  int e8 = threadIdx.x % 40;                 // 0..39 (8 elems each)
  int tok = (r < 256) ? in1[r * 128 + t] : in2[(r - 256) * 128 + t];
  const float* er = emb + (size_t)tok * EMB_D + e8 * 8;
  bf16x8 v;
  if (e8 < 37) {
#pragma unroll
    for (int i = 0; i < 8; ++i) v[i] = (bf16)er[i];
  } else {
#pragma unroll
    for (int i = 0; i < 8; ++i) {
      int e = e8 * 8 + i;
      v[i] = (e < EMB_D) ? (bf16)er[i] : (bf16)0.f;
    }
  }
  *reinterpret_cast<bf16x8*>(&xb[((size_t)t * N_ROWS + r) * KX + e8 * 8]) = v;
}

__global__ void pack_misc(const float* __restrict__ h1i, const float* __restrict__ h2i,
                          const float* __restrict__ bias, bf16* __restrict__ hb0,
                          float* __restrict__ biasp, unsigned* __restrict__ bar) {
  int idx = blockIdx.x * 256 + threadIdx.x;
  if (idx < N_ROWS * HID) {
    int r = idx >> 10, k = idx & 1023;
    float v = (r < 256) ? h1i[(size_t)r * HID + k] : h2i[(size_t)(r - 256) * HID + k];
    hb0[idx] = (bf16)v;
  }
  if (idx < 4096) {
    int cb = idx >> 6, g = (idx >> 4) & 3, c = idx & 15;
    biasp[idx] = bias[g * HID + cb * 16 + c];
    bar[idx] = 0u;   // reset all barrier lines (16 KB region) every launch
  }
}

// ---- cooperative LSTM recurrence ---------------------------------------
// grid 256 = 4 row-blocks x 64 col-groups. Block: 128 rows x 64 pcols
// (all 4 gates of 16 cells, p2 packing). Wave w owns rows w*32..+31:
//   acc[mi][ni][q] = G[row=w*32+mi*16+(lane>>4)*4+q][pcol=ni*16+(lane&15)]
//   gate = ni, cell = cb*16 + (lane&15): cell update fully in-register.
// r16: A-operands (x/h) loaded DIRECTLY global->VGPR per chunk — the MFMA
// A-fragment is 16 contiguous bytes of a row, and each wave's rows are
// exclusive, so no LDS staging needed. Coalescing: lanes l,l+16,l+32,l+48
// read one contiguous 64B of a row (wave = 16 rows x 64B). LDS carries only
// B (weights): 16 KB double-buffered, staged as r13/r14 (single-slot regs,
// issued 2 chunks ahead). Cuts per-chunk LDS traffic 72->40 KB and removes
// the A global->reg->LDS round trip. Flag-wait at kc==4 (h A-loads @ kc=5).
__launch_bounds__(256, 2)
__global__ void lstm_coop(const bf16* __restrict__ xb, const bf16* __restrict__ wbt,
                          bf16* __restrict__ hb, const float* __restrict__ biasp,
                          const float* __restrict__ c1i, const float* __restrict__ c2i,
                          const int* __restrict__ s1, const int* __restrict__ s2,
                          unsigned* __restrict__ bar) {
  __shared__ bf16 Bs[2][64][64];     // 16 KB total, XOR-swizzled 16B chunks
  const int tid = threadIdx.x;
  const int wave = tid >> 6;
  const int lane = tid & 63;
  const int lrow = lane & 15;
  const int hi = lane >> 4;        // 0..3
  const int l7 = lane & 7;
  const int bid = blockIdx.x;
  const int rb = bid >> 6;         // 0..3
  const int cb = bid & 63;         // 0..63
  const int r0 = rb * 128;

  const int cellabs = cb * 16 + lrow;    // this lane's cell column (orig order)

  int slen[2][4];     // per (mi,q): row = r0 + wave*32 + mi*16 + hi*4 + q
#pragma unroll
  for (int mi = 0; mi < 2; ++mi)
#pragma unroll
    for (int q = 0; q < 4; ++q) {
      int rr = r0 + wave * 32 + mi * 16 + hi * 4 + q;
      slen[mi][q] = (rr < 256) ? s1[rr] : s2[rr - 256];
    }

  float creg[2][4];   // [mi][q] cell state, f32 in registers
#pragma unroll
  for (int mi = 0; mi < 2; ++mi)
#pragma unroll
    for (int q = 0; q < 4; ++q) {
      int rr = r0 + wave * 32 + mi * 16 + hi * 4 + q;
      const float* cbp = (rr < 256) ? (c1i + (size_t)rr * HID)
                                    : (c2i + (size_t)(rr - 256) * HID);
      creg[mi][q] = cbp[cellabs];
    }

  // bias folded into accumulator init: acc[.][ni] col = ni*16+lrow = gate ni
  float bv[4];
#pragma unroll
  for (int ni = 0; ni < 4; ++ni)
    bv[ni] = biasp[cb * 64 + ni * 16 + lrow];

  // A-fragment row bases for this lane (frag rows: wave*32 + mi*16 + lrow)
  const int arow0 = r0 + wave * 32 + lrow;        // mi=0
  const int arow1 = arow0 + 16;                   // mi=1

  // B staging: 64 rows x 8 chunks, 4 threads/row, 2 chunks each. XOR swizzle:
  // chunk cc -> col ((cc ^ (row&7)) << 3).
  const int b_r = tid >> 2, b_cb = (tid & 3) * 2;

  bf16x8 rbv2[2];
  auto issue_b = [&](int nkc) {
    const bf16* bsrc = wbt + (size_t)(cb * 64 + b_r) * KTOT + nkc * 64 + b_cb * 8;
#pragma unroll
    for (int q = 0; q < 2; ++q)
      rbv2[q] = *reinterpret_cast<const bf16x8*>(bsrc + q * 8);
  };
  auto stage_b = [&](int buf) {
#pragma unroll
    for (int q = 0; q < 2; ++q)
      *reinterpret_cast<bf16x8*>(&Bs[buf][b_r][((b_cb + q) ^ (b_r & 7)) << 3]) = rbv2[q];
  };

  // prologue: buf0 <- B chunk 0; regs <- B chunk 1
  issue_b(0);
  stage_b(0);
  issue_b(1);
  __syncthreads();
  int db = 0;

  unsigned* ga    = bar + (bid & 7) * 16;   // own group arrive line (64B apart)
  unsigned* gsum  = bar + 128;              // summary line
  unsigned* flags = bar + 256;              // flag[t] at flags + t*16

  for (int t = 0; t < NSTEPS; ++t) {
    f32x4 acc[2][4];
#pragma unroll
    for (int mi = 0; mi < 2; ++mi)
#pragma unroll
      for (int ni = 0; ni < 4; ++ni)
        acc[mi][ni] = f32x4{bv[ni], bv[ni], bv[ni], bv[ni]};

    const bf16* xt = xb + (size_t)t * N_ROWS * KX;
    const bf16* hc0 = hb + ((size_t)(t & 1) << 19);

    for (int kc = 0; kc < 21; ++kc) {
      // A-fragments for THIS chunk: direct global->VGPR (issued early; the
      // B stage/issue below covers most of the L2 latency before MFMA use)
      bf16x8 afr[2][2];   // [mi][ks], constant-indexed (registers)
      {
        if (kc < 5) {
          const bf16* a0 = xt + (size_t)arow0 * KX + kc * 64 + hi * 8;
          const bf16* a1 = xt + (size_t)arow1 * KX + kc * 64 + hi * 8;
#pragma unroll
          for (int ks = 0; ks < 2; ++ks) {
            afr[0][ks] = *reinterpret_cast<const bf16x8*>(a0 + ks * 32);
            afr[1][ks] = *reinterpret_cast<const bf16x8*>(a1 + ks * 32);
          }
        } else {
          const bf16* a0 = hc0 + ((size_t)arow0 << 10) + (kc * 64 - KX) + hi * 8;
          const bf16* a1 = hc0 + ((size_t)arow1 << 10) + (kc * 64 - KX) + hi * 8;
#pragma unroll
          for (int ks = 0; ks < 2; ++ks) {
            afr[0][ks] = *reinterpret_cast<const bf16x8*>(a0 + ks * 32);
            afr[1][ks] = *reinterpret_cast<const bf16x8*>(a1 + ks * 32);
          }
        }
      }

      // stage B chunk kc+1 (regs invariant) into the other buffer
      stage_b(db ^ 1);

      // grid wait: peers' h(t) must be visible before the first h A-frag
      // load (kc==5, top of next iteration).
      if (kc == 4 && t > 0) {
        if (tid == 0) {
          const unsigned* fl = flags + (t - 1) * 16;
          while (__hip_atomic_load(fl, __ATOMIC_RELAXED, __HIP_MEMORY_SCOPE_AGENT) == 0u)
            __builtin_amdgcn_s_sleep(2);
          (void)__hip_atomic_load(fl, __ATOMIC_ACQUIRE, __HIP_MEMORY_SCOPE_AGENT);
        }
        __syncthreads();
      }

      // issue B loads for chunk kc+2 (weights only — no h dependency)
      {
        int nkc = kc + 2;
        if (nkc > 20) nkc -= 21;
        if (!(t == NSTEPS - 1 && kc >= 19)) issue_b(nkc);
      }

      // compute chunk kc: B frags from LDS, A frags from afr registers
#pragma unroll
      for (int ks = 0; ks < 2; ++ks) {
        const int cs = (((ks << 2) | hi) ^ l7) << 3;
        bf16x8 bfv[4];
#pragma unroll
        for (int ni = 0; ni < 4; ++ni)
          bfv[ni] = *reinterpret_cast<const bf16x8*>(&Bs[db][ni * 16 + lrow][cs]);
#pragma unroll
        for (int mi = 0; mi < 2; ++mi)
#pragma unroll
          for (int ni = 0; ni < 4; ++ni)
            acc[mi][ni] = __builtin_amdgcn_mfma_f32_16x16x32_bf16(
                afr[mi][ks], bfv[ni], acc[mi][ni], 0, 0, 0);
      }
      lds_barrier();   // lgkmcnt-only: B prefetch loads stay in flight
      db ^= 1;
    }

    // cell update: lane owns 8 rows x 1 cell, all 4 gates in-register (g=ni)
    {
      const size_t curo = (size_t)(t & 1) << 19;
      const bf16* hc = hb + curo;
      bf16* hnb = hb + (curo ^ ((size_t)1 << 19));
#pragma unroll
      for (int mi = 0; mi < 2; ++mi)
#pragma unroll
        for (int q = 0; q < 4; ++q) {
          float ig = acc[mi][0][q];
          float jg = acc[mi][1][q];
          float fg = acc[mi][2][q];
          float og = acc[mi][3][q];
          float cn = sigm(fg + 1.f) * creg[mi][q] + sigm(ig) * tanh_fast(jg);
          float hv = tanh_fast(cn) * sigm(og);
          int rr = r0 + wave * 32 + mi * 16 + hi * 4 + q;
          size_t off = ((size_t)rr << 10) + cellabs;
          float ho;
          if (t < slen[mi][q]) { creg[mi][q] = cn; ho = hv; }
          else ho = (float)hc[off];
          hnb[off] = (bf16)ho;
        }
    }

    // arrive: full __syncthreads (drains h stores) then hierarchical release
    // chain: ga (32 fan-in, 8 lines) -> gsum (8 fan-in) -> flag[t].
    __syncthreads();
    if (t < NSTEPS - 1 && tid == 0) {
      unsigned prev = __hip_atomic_fetch_add(ga, 1u, __ATOMIC_RELEASE,
                                             __HIP_MEMORY_SCOPE_AGENT);
      if ((prev & 31u) == 31u) {        // 32nd arrival of this step on this line
        (void)__hip_atomic_load(ga, __ATOMIC_ACQUIRE, __HIP_MEMORY_SCOPE_AGENT);
        unsigned p2 = __hip_atomic_fetch_add(gsum, 1u, __ATOMIC_RELEASE,
                                             __HIP_MEMORY_SCOPE_AGENT);
        if ((p2 & 7u) == 7u) {          // all 8 groups done
          (void)__hip_atomic_load(gsum, __ATOMIC_ACQUIRE, __HIP_MEMORY_SCOPE_AGENT);
          __hip_atomic_store(flags + t * 16, 1u, __ATOMIC_RELEASE,
                             __HIP_MEMORY_SCOPE_AGENT);
        }
      }
    }
  }
}

// ---- head ---------------------------------------------------------------
__global__ void feat_kernel(const bf16* __restrict__ hb0, const int* __restrict__ s1,
                            const int* __restrict__ s2, float* __restrict__ HC,
                            float* __restrict__ H2T) {
  int a = blockIdx.x;
  int tid = threadIdx.x;
  __shared__ float red[256];
  const bf16* h1r = hb0 + (size_t)a * HID;
  const bf16* h2r = hb0 + (size_t)(a + 256) * HID;
  float l1 = (float)s1[a] * (1.f / 128.f);
  float l2 = (float)s2[a] * (1.f / 128.f);
  float dacc = 0.f;
  for (int k = tid; k < 1025; k += 256) {
    float v1 = (k < HID) ? (float)h1r[k] : l1;
    float v2 = (k < HID) ? (float)h2r[k] : l2;
    HC[(size_t)a * HC_W + k] = v1;
    HC[(size_t)a * HC_W + 1025 + k] = v2;
    HC[(size_t)a * HC_W + 2051 + k] = v1 * v2;
    H2T[(size_t)k * 256 + a] = v2;
    float d = v1 - v2;
    dacc += d * d;
  }
  red[tid] = dacc;
  __syncthreads();
  for (int s = 128; s > 0; s >>= 1) {
    if (tid < s) red[tid] += red[tid + s];
    __syncthreads();
  }
  if (tid == 0) HC[(size_t)a * HC_W + 2050] = red[0];
}

// 8 rows/block (grid 5 x 32) — r11-proven
__global__ void t1_kernel(const float* __restrict__ HC, const float* __restrict__ Wh,
                          float* __restrict__ T1) {
  int j = blockIdx.x * 256 + threadIdx.x;
  int a0 = blockIdx.y * 8;
  __shared__ float sh[8][64];
  float acc[8];
#pragma unroll
  for (int r = 0; r < 8; ++r) acc[r] = 0.f;
  for (int kc = 0; kc < 1025; kc += 64) {
    int kn = (1025 - kc < 64) ? (1025 - kc) : 64;
    for (int idx = threadIdx.x; idx < 512; idx += 256) {
      int r = idx >> 6, kk = idx & 63;
      sh[r][kk] = (kk < kn) ? HC[(size_t)(a0 + r) * HC_W + kc + kk] : 0.f;
    }
    __syncthreads();
    if (j < 1025) {
      for (int kk = 0; kk < kn; ++kk) {
        float w = Wh[(size_t)(kc + kk) * 1025 + j];
#pragma unroll
        for (int r = 0; r < 8; ++r) acc[r] += sh[r][kk] * w;
      }
    }
    __syncthreads();
  }
  if (j < 1025) {
    for (int r = 0; r < 8; ++r) T1[(size_t)(a0 + r) * 1025 + j] = acc[r];
  }
}

__global__ void inter_kernel(const float* __restrict__ T1, const float* __restrict__ H2T,
                             float* __restrict__ HC) {
  int a0 = blockIdx.x * 8;
  int b = threadIdx.x;
  __shared__ float sT[8][1025];
  for (int idx = threadIdx.x; idx < 8 * 1025; idx += 256) {
    int r = idx / 1025, k = idx - r * 1025;
    sT[r][k] = T1[(size_t)(a0 + r) * 1025 + k];
  }
  __syncthreads();
  float acc[8];
#pragma unroll
  for (int r = 0; r < 8; ++r) acc[r] = 0.f;
  for (int k = 0; k < 1025; ++k) {
    float v = H2T[(size_t)k * 256 + b];
#pragma unroll
    for (int r = 0; r < 8; ++r) acc[r] += sT[r][k] * v;
  }
#pragma unroll
  for (int r = 0; r < 8; ++r)
    HC[(size_t)(a0 + r) * HC_W + 3076 + b] = acc[r];
}

__global__ void e1_kernel(const float* __restrict__ HC, const float* __restrict__ W1,
                          const float* __restrict__ b1, float* __restrict__ E1) {
  int a0 = blockIdx.x * 8;
  int j = blockIdx.y * 256 + threadIdx.x;
  __shared__ float sh[8][128];
  float acc[8];
#pragma unroll
  for (int r = 0; r < 8; ++r) acc[r] = 0.f;
  for (int kc = 0; kc < HC_W; kc += 128) {
    int kn = (HC_W - kc < 128) ? (HC_W - kc) : 128;
    for (int idx = threadIdx.x; idx < 1024; idx += 256) {
      int r = idx >> 7, kk = idx & 127;
      sh[r][kk] = (kk < kn) ? HC[(size_t)(a0 + r) * HC_W + kc + kk] : 0.f;
    }
    __syncthreads();
    for (int kk = 0; kk < kn; ++kk) {
      float w = W1[(size_t)(kc + kk) * 512 + j];
#pragma unroll
      for (int r = 0; r < 8; ++r) acc[r] += sh[r][kk] * w;
    }
    __syncthreads();
  }
  float bj = b1[j];
#pragma unroll
  for (int r = 0; r < 8; ++r)
    E1[(size_t)(a0 + r) * 512 + j] = fmaxf(acc[r] + bj, 0.f);
}

__global__ void out_kernel(const float* __restrict__ E1, const float* __restrict__ W2,
                           const float* __restrict__ b2, float* __restrict__ out) {
  int a = threadIdx.x;
  float a0 = 0.f, a1 = 0.f;
  const float* e = E1 + (size_t)a * 512;
  for (int k = 0; k < 512; ++k) {
    float v = e[k];
    a0 += v * W2[2 * k];
    a1 += v * W2[2 * k + 1];
  }
  out[2 * a] = a0 + b2[0];
  out[2 * a + 1] = a1 + b2[1];
}

// ---- host ---------------------------------------------------------------
extern "C" void kernel_launch(void* const* d_in, const int* in_sizes, int n_in,
                              void* d_out, int out_size, void* d_ws, size_t ws_size,
                              hipStream_t stream) {
  const int*   input1 = (const int*)d_in[0];
  const int*   input2 = (const int*)d_in[1];
  const int*   seql1  = (const int*)d_in[2];
  const int*   seql2  = (const int*)d_in[3];
  const float* emb    = (const float*)d_in[4];
  const float* lk     = (const float*)d_in[5];
  const float* lbias  = (const float*)d_in[6];
  const float* c1i    = (const float*)d_in[7];
  const float* h1i    = (const float*)d_in[8];
  const float* c2i    = (const float*)d_in[9];
  const float* h2i    = (const float*)d_in[10];
  const float* W_h    = (const float*)d_in[11];
  const float* W1     = (const float*)d_in[12];
  const float* b1     = (const float*)d_in[13];
  const float* W2     = (const float*)d_in[14];
  const float* b2     = (const float*)d_in[15];

  char* ws = (char*)d_ws;
  bf16*     WbT   = (bf16*)(ws + WBT_OFF);
  bf16*     Xb    = (bf16*)(ws + XB_OFF);
  bf16*     Hb    = (bf16*)(ws + HB_OFF);
  float*    biasp = (float*)(ws + BIASP_OFF);
  float*    HC    = (float*)(ws + HC_OFF);
  float*    H2T   = (float*)(ws + H2T_OFF);
  float*    T1    = (float*)(ws + T1_OFF);
  float*    E1    = (float*)(ws + E1_OFF);
  unsigned* bar   = (unsigned*)(ws + BAR_OFF);

  pack_wbt<<<dim3(16, 1344), 256, 0, stream>>>(lk, WbT);
  pack_xb<<<dim3(512, 16), 320, 0, stream>>>(input1, input2, emb, Xb);
  pack_misc<<<2048, 256, 0, stream>>>(h1i, h2i, lbias, Hb, biasp, bar);

  void* kargs[] = { (void*)&Xb, (void*)&WbT, (void*)&Hb, (void*)&biasp,
                    (void*)&c1i, (void*)&c2i, (void*)&seql1, (void*)&seql2,
                    (void*)&bar };
  hipLaunchCooperativeKernel((void*)lstm_coop, dim3(256), dim3(256), kargs, 0, stream);

  feat_kernel<<<256, 256, 0, stream>>>(Hb, seql1, seql2, HC, H2T);
  t1_kernel<<<dim3(5, 32), 256, 0, stream>>>(HC, W_h, T1);
  inter_kernel<<<32, 256, 0, stream>>>(T1, H2T, HC);
  e1_kernel<<<dim3(32, 2), 256, 0, stream>>>(HC, W1, b1, E1);
  out_kernel<<<1, 256, 0, stream>>>(E1, W2, b2, (float*)d_out);
}

// Round 17
// 4247.112 us; speedup vs baseline: 1.1328x; 1.0380x over previous
//
#include <hip/hip_runtime.h>
#include <hip/hip_bf16.h>

typedef __bf16 bf16;
typedef __bf16 bf16x8 __attribute__((ext_vector_type(8)));
typedef float f32x4 __attribute__((ext_vector_type(4)));

#define N_ROWS   512      // rows 0..255 seq1, 256..511 seq2
#define HID      1024
#define KX       320      // EMB=300 padded to 320
#define KTOT     1344     // 320 + 1024
#define NSTEPS   128
#define EMB_D    300
#define HC_W     3332     // 1025+1025+1+1025+256

// workspace layout (bytes)
#define WBT_OFF   0UL          // bf16 [4096][1344]  (packed p2 order, transposed)
#define XB_OFF    11010048UL   // bf16 [128][512][320]
#define HB_OFF    52953088UL   // bf16 [2][512][1024]
#define BIASP_OFF 55050240UL   // f32  [4096] (packed p2 order)
#define HC_OFF    55066624UL   // f32  [256][3332]
#define H2T_OFF   58478592UL   // f32  [1025][256]
#define T1_OFF    59528192UL   // f32  [256][1025]
#define E1_OFF    60577792UL   // f32  [256][512]
// barrier region (dwords from BAR_OFF):
//   ga[g]   at dword g*16   (g=0..7)   8 monotonic arrive lines, 64B apart
//   gsum    at dword 128               monotonic summary line
//   flag[t] at dword 256 + t*16        per-step flag lines (fresh each step)
#define BAR_OFF   61102080UL

// ENVELOPE RULE (16 rounds): coop kernel = 256-thread blocks, grid 256,
// __launch_bounds__(256,2), VGPR <= 128, static LDS <= ~61KB (hard fail >64KB).
// No multi-slot register staging arrays (remat blowup r7/r8/r11). Grid 512
// regresses (r15). A-operands direct from global regress (r16).
// r17: staging via global_load_lds (no staging VGPRs, no ds_writes) with
// counted s_waitcnt vmcnt(2) barriers (m201/HK pattern).

__device__ __forceinline__ float sigm(float x) { return 1.f / (1.f + __expf(-x)); }
__device__ __forceinline__ float tanh_fast(float x) {
  float xc = fminf(fmaxf(x, -15.f), 15.f);
  float e = __expf(2.f * xc);
  return (e - 1.f) / (e + 1.f);
}

__device__ __forceinline__ void gload16(const bf16* g, bf16* l) {
  __builtin_amdgcn_global_load_lds(
      (const __attribute__((address_space(1))) void*)g,
      (__attribute__((address_space(3))) void*)l, 16, 0, 0);
}

// ---- pack kernels -------------------------------------------------------
// packed order: p2 = cb*64 + g*16 + c  <->  orig col g*1024 + cb*16 + c
__global__ void pack_wbt(const float* __restrict__ lk, bf16* __restrict__ wbt) {
  int p = blockIdx.x * 256 + threadIdx.x;   // 0..4095
  int k = blockIdx.y;                        // 0..1343
  int cb = p >> 6, g = (p >> 4) & 3, c = p & 15;
  int oc = g * HID + cb * 16 + c;
  float v = 0.f;
  if (k < KX) { if (k < EMB_D) v = lk[(size_t)k * 4096 + oc]; }
  else v = lk[(size_t)(EMB_D + k - KX) * 4096 + oc];
  wbt[(size_t)p * KTOT + k] = (bf16)v;
}

// vectorized bf16x8 writes; block 320 = 8 timesteps x 40 e-groups (r11-proven)
__global__ void pack_xb(const int* __restrict__ in1, const int* __restrict__ in2,
                        const float* __restrict__ emb, bf16* __restrict__ xb) {
  int r = blockIdx.x;                        // 0..511
  int t = blockIdx.y * 8 + threadIdx.x / 40; // 0..127
  int e8 = threadIdx.x % 40;                 // 0..39 (8 elems each)
  int tok = (r < 256) ? in1[r * 128 + t] : in2[(r - 256) * 128 + t];
  const float* er = emb + (size_t)tok * EMB_D + e8 * 8;
  bf16x8 v;
  if (e8 < 37) {
#pragma unroll
    for (int i = 0; i < 8; ++i) v[i] = (bf16)er[i];
  } else {
#pragma unroll
    for (int i = 0; i < 8; ++i) {
      int e = e8 * 8 + i;
      v[i] = (e < EMB_D) ? (bf16)er[i] : (bf16)0.f;
    }
  }
  *reinterpret_cast<bf16x8*>(&xb[((size_t)t * N_ROWS + r) * KX + e8 * 8]) = v;
}

__global__ void pack_misc(const float* __restrict__ h1i, const float* __restrict__ h2i,
                          const float* __restrict__ bias, bf16* __restrict__ hb0,
                          float* __restrict__ biasp, unsigned* __restrict__ bar) {
  int idx = blockIdx.x * 256 + threadIdx.x;
  if (idx < N_ROWS * HID) {
    int r = idx >> 10, k = idx & 1023;
    float v = (r < 256) ? h1i[(size_t)r * HID + k] : h2i[(size_t)(r - 256) * HID + k];
    hb0[idx] = (bf16)v;
  }
  if (idx < 4096) {
    int cb = idx >> 6, g = (idx >> 4) & 3, c = idx & 15;
    biasp[idx] = bias[g * HID + cb * 16 + c];
    bar[idx] = 0u;   // reset all barrier lines (16 KB region) every launch
  }
}

// ---- cooperative LSTM recurrence ---------------------------------------
// grid 256 = 4 row-blocks x 64 col-groups. Block: 128 rows x 64 pcols
// (all 4 gates of 16 cells, p2 packing). Wave w owns rows w*32..+31:
//   acc[mi][ni][q] = G[row=w*32+mi*16+(lane>>4)*4+q][pcol=ni*16+(lane&15)]
//   gate = ni, cell = cb*16 + (lane&15): cell update fully in-register.
// r17 staging: global_load_lds direct to LDS. A dbuf (2x16KB, depth 1),
// B tribuf (3x8KB, depth 2). Swizzled layout achieved by pre-swizzling the
// per-lane GLOBAL source chunk: c_g = (lane&7)^(lane>>3) (G21 pattern);
// read side identical to r13 (zero bank conflicts). Per-chunk barrier:
// s_waitcnt vmcnt(2) lgkmcnt(0) + s_barrier — leaves the 2 newest B loads
// (chunk kc+2) in flight across the barrier. Issue order: A then B.
__launch_bounds__(256, 2)
__global__ void lstm_coop(const bf16* __restrict__ xb, const bf16* __restrict__ wbt,
                          bf16* __restrict__ hb, const float* __restrict__ biasp,
                          const float* __restrict__ c1i, const float* __restrict__ c2i,
                          const int* __restrict__ s1, const int* __restrict__ s2,
                          unsigned* __restrict__ bar) {
  __shared__ bf16 Ab[2][128][64];    // 32 KB
  __shared__ bf16 Bb[3][64][64];     // 24 KB  (total 56 KB)
  const int tid = threadIdx.x;
  const int wave = tid >> 6;
  const int lane = tid & 63;
  const int lrow = lane & 15;
  const int hi = lane >> 4;        // 0..3
  const int l7 = lane & 7;
  const int bid = blockIdx.x;
  const int rb = bid >> 6;         // 0..3
  const int cb = bid & 63;         // 0..63
  const int r0 = rb * 128;

  const int cellabs = cb * 16 + lrow;    // this lane's cell column (orig order)

  int slen[2][4];     // per (mi,q): row = r0 + wave*32 + mi*16 + hi*4 + q
#pragma unroll
  for (int mi = 0; mi < 2; ++mi)
#pragma unroll
    for (int q = 0; q < 4; ++q) {
      int rr = r0 + wave * 32 + mi * 16 + hi * 4 + q;
      slen[mi][q] = (rr < 256) ? s1[rr] : s2[rr - 256];
    }

  float creg[2][4];   // [mi][q] cell state, f32 in registers
#pragma unroll
  for (int mi = 0; mi < 2; ++mi)
#pragma unroll
    for (int q = 0; q < 4; ++q) {
      int rr = r0 + wave * 32 + mi * 16 + hi * 4 + q;
      const float* cbp = (rr < 256) ? (c1i + (size_t)rr * HID)
                                    : (c2i + (size_t)(rr - 256) * HID);
      creg[mi][q] = cbp[cellabs];
    }

  // bias folded into accumulator init: acc[.][ni] col = ni*16+lrow = gate ni
  float bv[4];
#pragma unroll
  for (int ni = 0; ni < 4; ++ni)
    bv[ni] = biasp[cb * 64 + ni * 16 + lrow];

  // gload_lds lane mapping: lane l -> LDS row +l/8, LDS chunk l%8, fetching
  // GLOBAL chunk cg = (l%8)^(l/8) (pre-swizzled source; row&7 == l/8).
  const int gl_rg = lane >> 3;            // 0..7 row within 8-row group
  const int gl_cg = (lane & 7) ^ gl_rg;   // swizzled global chunk (lane-const)

  // A: wave w covers rows w*32 + i*8 + gl_rg, i=0..3 (one instr per i)
  auto issue_a = [&](int nt, int nkc) {
#pragma unroll
    for (int i = 0; i < 4; ++i) {
      const int rl = wave * 32 + i * 8 + gl_rg;
      const bf16* src = (nkc < 5)
          ? (xb + ((size_t)nt * N_ROWS + r0 + rl) * KX + nkc * 64 + gl_cg * 8)
          : (hb + ((size_t)(nt & 1) << 19) + ((size_t)(r0 + rl) << 10) +
             (nkc * 64 - KX) + gl_cg * 8);
      gload16(src, &Ab[0][0][0] + (size_t)0);  // placeholder overwritten below
    }
  };
  (void)issue_a;  // not used; explicit versions below keep lds base uniform

  unsigned* ga    = bar + (bid & 7) * 16;   // own group arrive line (64B apart)
  unsigned* gsum  = bar + 128;              // summary line
  unsigned* flags = bar + 256;              // flag[t] at flags + t*16

#define ISSUE_A(ABUF, NT, NKC)                                                 \
  {                                                                            \
    _Pragma("unroll")                                                          \
    for (int i_ = 0; i_ < 4; ++i_) {                                           \
      const int rl_ = wave * 32 + i_ * 8 + gl_rg;                              \
      const bf16* src_ = ((NKC) < 5)                                           \
          ? (xb + ((size_t)(NT) * N_ROWS + r0 + rl_) * KX + (NKC) * 64 +       \
             gl_cg * 8)                                                        \
          : (hb + ((size_t)((NT) & 1) << 19) + ((size_t)(r0 + rl_) << 10) +    \
             ((NKC) * 64 - KX) + gl_cg * 8);                                   \
      gload16(src_, &Ab[(ABUF)][wave * 32 + i_ * 8][0]);                       \
    }                                                                          \
  }
#define ISSUE_B(BBUF, NKC)                                                     \
  {                                                                            \
    _Pragma("unroll")                                                          \
    for (int i_ = 0; i_ < 2; ++i_) {                                           \
      const int rl_ = wave * 16 + i_ * 8 + gl_rg;                              \
      const bf16* src_ =                                                       \
          wbt + (size_t)(cb * 64 + rl_) * KTOT + (NKC) * 64 + gl_cg * 8;       \
      gload16(src_, &Bb[(BBUF)][wave * 16 + i_ * 8][0]);                       \
    }                                                                          \
  }

  // prologue: A(0)->Ab0, B(0)->Bb0, B(1)->Bb1; wait all but B(1)'s 2 loads
  ISSUE_A(0, 0, 0)
  ISSUE_B(0, 0)
  ISSUE_B(1, 1)
  asm volatile("s_waitcnt vmcnt(2) lgkmcnt(0)" ::: "memory");
  __builtin_amdgcn_sched_barrier(0);
  __builtin_amdgcn_s_barrier();
  __builtin_amdgcn_sched_barrier(0);

  int ab = 0, bb = 0;

  for (int t = 0; t < NSTEPS; ++t) {
    f32x4 acc[2][4];
#pragma unroll
    for (int mi = 0; mi < 2; ++mi)
#pragma unroll
      for (int ni = 0; ni < 4; ++ni)
        acc[mi][ni] = f32x4{bv[ni], bv[ni], bv[ni], bv[ni]};

    for (int kc = 0; kc < 21; ++kc) {
      // grid wait BEFORE issuing the first h A-load (nkc=5 at kc==4)
      if (kc == 4 && t > 0) {
        if (tid == 0) {
          const unsigned* fl = flags + (t - 1) * 16;
          while (__hip_atomic_load(fl, __ATOMIC_RELAXED, __HIP_MEMORY_SCOPE_AGENT) == 0u)
            __builtin_amdgcn_s_sleep(2);
          (void)__hip_atomic_load(fl, __ATOMIC_ACQUIRE, __HIP_MEMORY_SCOPE_AGENT);
        }
        __syncthreads();
      }

      // issue A(kc+1) into Ab[ab^1]  (wraps to next step's chunk 0)
      if (!(t == NSTEPS - 1 && kc == 20)) {
        int nkc = kc + 1, nt = t;
        if (nkc > 20) { nkc -= 21; ++nt; }
        ISSUE_A(ab ^ 1, nt, nkc)
      }
      // issue B(kc+2) into Bb[(bb+2)%3]  (weights, no h dependency)
      if (!(t == NSTEPS - 1 && kc >= 19)) {
        int nkc = kc + 2;
        if (nkc > 20) nkc -= 21;
        const int bt = (bb + 2) % 3;
        ISSUE_B(bt, nkc)
      }

      // compute chunk kc from Ab[ab], Bb[bb]
#pragma unroll
      for (int ks = 0; ks < 2; ++ks) {
        const int cs = (((ks << 2) | hi) ^ l7) << 3;
        bf16x8 af[2], bfv[4];
#pragma unroll
        for (int mi = 0; mi < 2; ++mi)
          af[mi] = *reinterpret_cast<const bf16x8*>(
              &Ab[ab][wave * 32 + mi * 16 + lrow][cs]);
#pragma unroll
        for (int ni = 0; ni < 4; ++ni)
          bfv[ni] = *reinterpret_cast<const bf16x8*>(&Bb[bb][ni * 16 + lrow][cs]);
#pragma unroll
        for (int mi = 0; mi < 2; ++mi)
#pragma unroll
          for (int ni = 0; ni < 4; ++ni)
            acc[mi][ni] = __builtin_amdgcn_mfma_f32_16x16x32_bf16(
                af[mi], bfv[ni], acc[mi][ni], 0, 0, 0);
      }

      // counted-vmcnt barrier: drain A(kc+1) + B(kc+1); keep B(kc+2) in flight
      asm volatile("s_waitcnt vmcnt(2) lgkmcnt(0)" ::: "memory");
      __builtin_amdgcn_sched_barrier(0);
      __builtin_amdgcn_s_barrier();
      __builtin_amdgcn_sched_barrier(0);
      ab ^= 1;
      bb = (bb + 1) % 3;
    }

    // cell update: lane owns 8 rows x 1 cell, all 4 gates in-register (g=ni)
    {
      const size_t curo = (size_t)(t & 1) << 19;
      const bf16* hc = hb + curo;
      bf16* hnb = hb + (curo ^ ((size_t)1 << 19));
#pragma unroll
      for (int mi = 0; mi < 2; ++mi)
#pragma unroll
        for (int q = 0; q < 4; ++q) {
          float ig = acc[mi][0][q];
          float jg = acc[mi][1][q];
          float fg = acc[mi][2][q];
          float og = acc[mi][3][q];
          float cn = sigm(fg + 1.f) * creg[mi][q] + sigm(ig) * tanh_fast(jg);
          float hv = tanh_fast(cn) * sigm(og);
          int rr = r0 + wave * 32 + mi * 16 + hi * 4 + q;
          size_t off = ((size_t)rr << 10) + cellabs;
          float ho;
          if (t < slen[mi][q]) { creg[mi][q] = cn; ho = hv; }
          else ho = (float)hc[off];
          hnb[off] = (bf16)ho;
        }
    }

    // arrive: full __syncthreads (drains h stores) then hierarchical release
    // chain: ga (32 fan-in, 8 lines) -> gsum (8 fan-in) -> flag[t].
    __syncthreads();
    if (t < NSTEPS - 1 && tid == 0) {
      unsigned prev = __hip_atomic_fetch_add(ga, 1u, __ATOMIC_RELEASE,
                                             __HIP_MEMORY_SCOPE_AGENT);
      if ((prev & 31u) == 31u) {        // 32nd arrival of this step on this line
        (void)__hip_atomic_load(ga, __ATOMIC_ACQUIRE, __HIP_MEMORY_SCOPE_AGENT);
        unsigned p2 = __hip_atomic_fetch_add(gsum, 1u, __ATOMIC_RELEASE,
                                             __HIP_MEMORY_SCOPE_AGENT);
        if ((p2 & 7u) == 7u) {          // all 8 groups done
          (void)__hip_atomic_load(gsum, __ATOMIC_ACQUIRE, __HIP_MEMORY_SCOPE_AGENT);
          __hip_atomic_store(flags + t * 16, 1u, __ATOMIC_RELEASE,
                             __HIP_MEMORY_SCOPE_AGENT);
        }
      }
    }
  }
#undef ISSUE_A
#undef ISSUE_B
}

// ---- head ---------------------------------------------------------------
__global__ void feat_kernel(const bf16* __restrict__ hb0, const int* __restrict__ s1,
                            const int* __restrict__ s2, float* __restrict__ HC,
                            float* __restrict__ H2T) {
  int a = blockIdx.x;
  int tid = threadIdx.x;
  __shared__ float red[256];
  const bf16* h1r = hb0 + (size_t)a * HID;
  const bf16* h2r = hb0 + (size_t)(a + 256) * HID;
  float l1 = (float)s1[a] * (1.f / 128.f);
  float l2 = (float)s2[a] * (1.f / 128.f);
  float dacc = 0.f;
  for (int k = tid; k < 1025; k += 256) {
    float v1 = (k < HID) ? (float)h1r[k] : l1;
    float v2 = (k < HID) ? (float)h2r[k] : l2;
    HC[(size_t)a * HC_W + k] = v1;
    HC[(size_t)a * HC_W + 1025 + k] = v2;
    HC[(size_t)a * HC_W + 2051 + k] = v1 * v2;
    H2T[(size_t)k * 256 + a] = v2;
    float d = v1 - v2;
    dacc += d * d;
  }
  red[tid] = dacc;
  __syncthreads();
  for (int s = 128; s > 0; s >>= 1) {
    if (tid < s) red[tid] += red[tid + s];
    __syncthreads();
  }
  if (tid == 0) HC[(size_t)a * HC_W + 2050] = red[0];
}

// 8 rows/block (grid 5 x 32) — r11-proven
__global__ void t1_kernel(const float* __restrict__ HC, const float* __restrict__ Wh,
                          float* __restrict__ T1) {
  int j = blockIdx.x * 256 + threadIdx.x;
  int a0 = blockIdx.y * 8;
  __shared__ float sh[8][64];
  float acc[8];
#pragma unroll
  for (int r = 0; r < 8; ++r) acc[r] = 0.f;
  for (int kc = 0; kc < 1025; kc += 64) {
    int kn = (1025 - kc < 64) ? (1025 - kc) : 64;
    for (int idx = threadIdx.x; idx < 512; idx += 256) {
      int r = idx >> 6, kk = idx & 63;
      sh[r][kk] = (kk < kn) ? HC[(size_t)(a0 + r) * HC_W + kc + kk] : 0.f;
    }
    __syncthreads();
    if (j < 1025) {
      for (int kk = 0; kk < kn; ++kk) {
        float w = Wh[(size_t)(kc + kk) * 1025 + j];
#pragma unroll
        for (int r = 0; r < 8; ++r) acc[r] += sh[r][kk] * w;
      }
    }
    __syncthreads();
  }
  if (j < 1025) {
    for (int r = 0; r < 8; ++r) T1[(size_t)(a0 + r) * 1025 + j] = acc[r];
  }
}

__global__ void inter_kernel(const float* __restrict__ T1, const float* __restrict__ H2T,
                             float* __restrict__ HC) {
  int a0 = blockIdx.x * 8;
  int b = threadIdx.x;
  __shared__ float sT[8][1025];
  for (int idx = threadIdx.x; idx < 8 * 1025; idx += 256) {
    int r = idx / 1025, k = idx - r * 1025;
    sT[r][k] = T1[(size_t)(a0 + r) * 1025 + k];
  }
  __syncthreads();
  float acc[8];
#pragma unroll
  for (int r = 0; r < 8; ++r) acc[r] = 0.f;
  for (int k = 0; k < 1025; ++k) {
    float v = H2T[(size_t)k * 256 + b];
#pragma unroll
    for (int r = 0; r < 8; ++r) acc[r] += sT[r][k] * v;
  }
#pragma unroll
  for (int r = 0; r < 8; ++r)
    HC[(size_t)(a0 + r) * HC_W + 3076 + b] = acc[r];
}

__global__ void e1_kernel(const float* __restrict__ HC, const float* __restrict__ W1,
                          const float* __restrict__ b1, float* __restrict__ E1) {
  int a0 = blockIdx.x * 8;
  int j = blockIdx.y * 256 + threadIdx.x;
  __shared__ float sh[8][128];
  float acc[8];
#pragma unroll
  for (int r = 0; r < 8; ++r) acc[r] = 0.f;
  for (int kc = 0; kc < HC_W; kc += 128) {
    int kn = (HC_W - kc < 128) ? (HC_W - kc) : 128;
    for (int idx = threadIdx.x; idx < 1024; idx += 256) {
      int r = idx >> 7, kk = idx & 127;
      sh[r][kk] = (kk < kn) ? HC[(size_t)(a0 + r) * HC_W + kc + kk] : 0.f;
    }
    __syncthreads();
    for (int kk = 0; kk < kn; ++kk) {
      float w = W1[(size_t)(kc + kk) * 512 + j];
#pragma unroll
      for (int r = 0; r < 8; ++r) acc[r] += sh[r][kk] * w;
    }
    __syncthreads();
  }
  float bj = b1[j];
#pragma unroll
  for (int r = 0; r < 8; ++r)
    E1[(size_t)(a0 + r) * 512 + j] = fmaxf(acc[r] + bj, 0.f);
}

__global__ void out_kernel(const float* __restrict__ E1, const float* __restrict__ W2,
                           const float* __restrict__ b2, float* __restrict__ out) {
  int a = threadIdx.x;
  float a0 = 0.f, a1 = 0.f;
  const float* e = E1 + (size_t)a * 512;
  for (int k = 0; k < 512; ++k) {
    float v = e[k];
    a0 += v * W2[2 * k];
    a1 += v * W2[2 * k + 1];
  }
  out[2 * a] = a0 + b2[0];
  out[2 * a + 1] = a1 + b2[1];
}

// ---- host ---------------------------------------------------------------
extern "C" void kernel_launch(void* const* d_in, const int* in_sizes, int n_in,
                              void* d_out, int out_size, void* d_ws, size_t ws_size,
                              hipStream_t stream) {
  const int*   input1 = (const int*)d_in[0];
  const int*   input2 = (const int*)d_in[1];
  const int*   seql1  = (const int*)d_in[2];
  const int*   seql2  = (const int*)d_in[3];
  const float* emb    = (const float*)d_in[4];
  const float* lk     = (const float*)d_in[5];
  const float* lbias  = (const float*)d_in[6];
  const float* c1i    = (const float*)d_in[7];
  const float* h1i    = (const float*)d_in[8];
  const float* c2i    = (const float*)d_in[9];
  const float* h2i    = (const float*)d_in[10];
  const float* W_h    = (const float*)d_in[11];
  const float* W1     = (const float*)d_in[12];
  const float* b1     = (const float*)d_in[13];
  const float* W2     = (const float*)d_in[14];
  const float* b2     = (const float*)d_in[15];

  char* ws = (char*)d_ws;
  bf16*     WbT   = (bf16*)(ws + WBT_OFF);
  bf16*     Xb    = (bf16*)(ws + XB_OFF);
  bf16*     Hb    = (bf16*)(ws + HB_OFF);
  float*    biasp = (float*)(ws + BIASP_OFF);
  float*    HC    = (float*)(ws + HC_OFF);
  float*    H2T   = (float*)(ws + H2T_OFF);
  float*    T1    = (float*)(ws + T1_OFF);
  float*    E1    = (float*)(ws + E1_OFF);
  unsigned* bar   = (unsigned*)(ws + BAR_OFF);

  pack_wbt<<<dim3(16, 1344), 256, 0, stream>>>(lk, WbT);
  pack_xb<<<dim3(512, 16), 320, 0, stream>>>(input1, input2, emb, Xb);
  pack_misc<<<2048, 256, 0, stream>>>(h1i, h2i, lbias, Hb, biasp, bar);

  void* kargs[] = { (void*)&Xb, (void*)&WbT, (void*)&Hb, (void*)&biasp,
                    (void*)&c1i, (void*)&c2i, (void*)&seql1, (void*)&seql2,
                    (void*)&bar };
  hipLaunchCooperativeKernel((void*)lstm_coop, dim3(256), dim3(256), kargs, 0, stream);

  feat_kernel<<<256, 256, 0, stream>>>(Hb, seql1, seql2, HC, H2T);
  t1_kernel<<<dim3(5, 32), 256, 0, stream>>>(HC, W_h, T1);
  inter_kernel<<<32, 256, 0, stream>>>(T1, H2T, HC);
  e1_kernel<<<dim3(32, 2), 256, 0, stream>>>(HC, W1, b1, E1);
  out_kernel<<<1, 256, 0, stream>>>(E1, W2, b2, (float*)d_out);
}

// Round 18
// 2673.460 us; speedup vs baseline: 1.7995x; 1.5886x over previous
//
#include <hip/hip_runtime.h>
#include <hip/hip_bf16.h>

typedef __bf16 bf16;
typedef __bf16 bf16x8 __attribute__((ext_vector_type(8)));
typedef float f32x4 __attribute__((ext_vector_type(4)));

#define N_ROWS   512      // rows 0..255 seq1, 256..511 seq2
#define HID      1024
#define KX       320      // EMB=300 padded to 320
#define KTOT     1344     // 320 + 1024
#define NSTEPS   128
#define EMB_D    300
#define HC_W     3332     // 1025+1025+1+1025+256

// workspace layout (bytes) — lstm phase:
#define WBT_OFF   0UL          // bf16 [4096][1344]  (packed p2 order)
#define XB_OFF    11010048UL   // bf16 [128][512][320]
#define HB_OFF    52953088UL   // bf16 [2][512][1024]
#define BIASP_OFF 55050240UL   // f32  [4096] (packed p2 order)
#define CB_OFF    55066624UL   // f32  [512][1024] cell state (ends 57,163,776)
// head phase (aliases Xb, which is dead after the recurrence):
#define HC_OFF    11010048UL   // f32 [256][3332]
#define H2T_OFF   14422016UL   // f32 [1025][256]
#define T1_OFF    15471616UL   // f32 [256][1025]
#define E1_OFF    16521216UL   // f32 [256][512]

// r18: NO cooperative kernel. The recurrence runs as 128 graph-captured
// per-step launches (r13 inner loop verbatim, all barrier/flag/atomic code
// deleted). Kernel boundaries give inter-step ordering + cross-XCD h
// visibility. Cell state c lives in global f32 [512][1024] (2 MB).

__device__ __forceinline__ float sigm(float x) { return 1.f / (1.f + __expf(-x)); }
__device__ __forceinline__ float tanh_fast(float x) {
  float xc = fminf(fmaxf(x, -15.f), 15.f);
  float e = __expf(2.f * xc);
  return (e - 1.f) / (e + 1.f);
}

// LDS-only barrier (r14-proven): does not drain vmcnt.
__device__ __forceinline__ void lds_barrier() {
  asm volatile("s_waitcnt lgkmcnt(0)" ::: "memory");
  __builtin_amdgcn_sched_barrier(0);
  __builtin_amdgcn_s_barrier();
  __builtin_amdgcn_sched_barrier(0);
}

// ---- pack kernels -------------------------------------------------------
// packed order: p2 = cb*64 + g*16 + c  <->  orig col g*1024 + cb*16 + c
__global__ void pack_wbt(const float* __restrict__ lk, bf16* __restrict__ wbt) {
  int p = blockIdx.x * 256 + threadIdx.x;   // 0..4095
  int k = blockIdx.y;                        // 0..1343
  int cb = p >> 6, g = (p >> 4) & 3, c = p & 15;
  int oc = g * HID + cb * 16 + c;
  float v = 0.f;
  if (k < KX) { if (k < EMB_D) v = lk[(size_t)k * 4096 + oc]; }
  else v = lk[(size_t)(EMB_D + k - KX) * 4096 + oc];
  wbt[(size_t)p * KTOT + k] = (bf16)v;
}

// vectorized bf16x8 writes; block 320 = 8 timesteps x 40 e-groups (r11-proven)
__global__ void pack_xb(const int* __restrict__ in1, const int* __restrict__ in2,
                        const float* __restrict__ emb, bf16* __restrict__ xb) {
  int r = blockIdx.x;                        // 0..511
  int t = blockIdx.y * 8 + threadIdx.x / 40; // 0..127
  int e8 = threadIdx.x % 40;                 // 0..39 (8 elems each)
  int tok = (r < 256) ? in1[r * 128 + t] : in2[(r - 256) * 128 + t];
  const float* er = emb + (size_t)tok * EMB_D + e8 * 8;
  bf16x8 v;
  if (e8 < 37) {
#pragma unroll
    for (int i = 0; i < 8; ++i) v[i] = (bf16)er[i];
  } else {
#pragma unroll
    for (int i = 0; i < 8; ++i) {
      int e = e8 * 8 + i;
      v[i] = (e < EMB_D) ? (bf16)er[i] : (bf16)0.f;
    }
  }
  *reinterpret_cast<bf16x8*>(&xb[((size_t)t * N_ROWS + r) * KX + e8 * 8]) = v;
}

__global__ void pack_misc(const float* __restrict__ h1i, const float* __restrict__ h2i,
                          const float* __restrict__ c1i, const float* __restrict__ c2i,
                          const float* __restrict__ bias, bf16* __restrict__ hb0,
                          float* __restrict__ biasp, float* __restrict__ Cb) {
  int idx = blockIdx.x * 256 + threadIdx.x;
  if (idx < N_ROWS * HID) {
    int r = idx >> 10, k = idx & 1023;
    float v = (r < 256) ? h1i[(size_t)r * HID + k] : h2i[(size_t)(r - 256) * HID + k];
    hb0[idx] = (bf16)v;
    float cv = (r < 256) ? c1i[(size_t)r * HID + k] : c2i[(size_t)(r - 256) * HID + k];
    Cb[idx] = cv;
  }
  if (idx < 4096) {
    int cb = idx >> 6, g = (idx >> 4) & 3, c = idx & 15;
    biasp[idx] = bias[g * HID + cb * 16 + c];
  }
}

// ---- per-step LSTM kernel (r13 inner loop, no barriers) -----------------
// grid 256 = 4 row-blocks x 64 col-groups. Block: 128 rows x 64 pcols
// (all 4 gates of 16 cells, p2 packing). Wave w owns rows w*32..+31:
//   acc[mi][ni][q] = G[row=w*32+mi*16+(lane>>4)*4+q][pcol=ni*16+(lane&15)]
//   gate = ni, cell = cb*16 + (lane&15): cell update fully in-register.
// Double-buffered As/Bs (48 KB), single-slot reg staging issued 2 chunks
// ahead, lgkm-only barrier per chunk. c from/to global f32 [512][1024].
__launch_bounds__(256, 2)
__global__ void lstm_step(const bf16* __restrict__ xb, const bf16* __restrict__ wbt,
                          bf16* __restrict__ hb, const float* __restrict__ biasp,
                          float* __restrict__ Cb, const int* __restrict__ s1,
                          const int* __restrict__ s2, int t) {
  __shared__ bf16 As[2][128][64];    // 32 KB, XOR-swizzled 16B chunks
  __shared__ bf16 Bs[2][64][64];     // 16 KB  (total 48 KB)
  const int tid = threadIdx.x;
  const int wave = tid >> 6;
  const int lane = tid & 63;
  const int lrow = lane & 15;
  const int hi = lane >> 4;        // 0..3
  const int l7 = lane & 7;
  const int bid = blockIdx.x;
  const int rb = bid >> 6;         // 0..3
  const int cb = bid & 63;         // 0..63
  const int r0 = rb * 128;

  const int cellabs = cb * 16 + lrow;    // this lane's cell column (0..1023)

  int slen[2][4];
#pragma unroll
  for (int mi = 0; mi < 2; ++mi)
#pragma unroll
    for (int q = 0; q < 4; ++q) {
      int rr = r0 + wave * 32 + mi * 16 + hi * 4 + q;
      slen[mi][q] = (rr < 256) ? s1[rr] : s2[rr - 256];
    }

  float creg[2][4];   // cell state from global
#pragma unroll
  for (int mi = 0; mi < 2; ++mi)
#pragma unroll
    for (int q = 0; q < 4; ++q) {
      int rr = r0 + wave * 32 + mi * 16 + hi * 4 + q;
      creg[mi][q] = Cb[(size_t)rr * HID + cellabs];
    }

  float bv[4];
#pragma unroll
  for (int ni = 0; ni < 4; ++ni)
    bv[ni] = biasp[cb * 64 + ni * 16 + lrow];

  // staging thread mapping (r13-proven): A 128 rows x 8 chunks (2 thr/row,
  // 4 chunks each); B 64 rows x 8 chunks (4 thr/row, 2 chunks each).
  // XOR swizzle: chunk cc -> col ((cc ^ (row&7)) << 3).
  const int a_r = tid >> 1, a_cb = (tid & 1) * 4;
  const int b_r = tid >> 2, b_cb = (tid & 3) * 2;

  const bf16* xt = xb + (size_t)t * N_ROWS * KX;
  const bf16* hc0 = hb + ((size_t)(t & 1) << 19);

  bf16x8 ra[4], rbv2[2];
  auto issue_loads = [&](int nkc) {
    const bf16* asrc = (nkc < 5)
        ? (xt + (size_t)(r0 + a_r) * KX + nkc * 64 + a_cb * 8)
        : (hc0 + ((size_t)(r0 + a_r) << 10) + (nkc * 64 - KX) + a_cb * 8);
#pragma unroll
    for (int q = 0; q < 4; ++q)
      ra[q] = *reinterpret_cast<const bf16x8*>(asrc + q * 8);
    const bf16* bsrc = wbt + (size_t)(cb * 64 + b_r) * KTOT + nkc * 64 + b_cb * 8;
#pragma unroll
    for (int q = 0; q < 2; ++q)
      rbv2[q] = *reinterpret_cast<const bf16x8*>(bsrc + q * 8);
  };
  auto stage_to = [&](int buf) {
#pragma unroll
    for (int q = 0; q < 4; ++q)
      *reinterpret_cast<bf16x8*>(&As[buf][a_r][((a_cb + q) ^ (a_r & 7)) << 3]) = ra[q];
#pragma unroll
    for (int q = 0; q < 2; ++q)
      *reinterpret_cast<bf16x8*>(&Bs[buf][b_r][((b_cb + q) ^ (b_r & 7)) << 3]) = rbv2[q];
  };

  // prologue: buf0 <- chunk 0; regs <- chunk 1
  issue_loads(0);
  stage_to(0);
  issue_loads(1);
  __syncthreads();
  int db = 0;

  f32x4 acc[2][4];
#pragma unroll
  for (int mi = 0; mi < 2; ++mi)
#pragma unroll
    for (int ni = 0; ni < 4; ++ni)
      acc[mi][ni] = f32x4{bv[ni], bv[ni], bv[ni], bv[ni]};

  for (int kc = 0; kc < 21; ++kc) {
    // stage chunk kc+1 (regs invariant) into the other buffer
    if (kc < 20) stage_to(db ^ 1);

    // issue loads for chunk kc+2
    {
      int nkc = kc + 2;
      if (nkc <= 20) issue_loads(nkc);
    }

    // compute chunk kc from buf[db]: per ks, 2 A-frags + 4 B-frags, 8 MFMAs
#pragma unroll
    for (int ks = 0; ks < 2; ++ks) {
      const int cs = (((ks << 2) | hi) ^ l7) << 3;
      bf16x8 af[2], bfv[4];
#pragma unroll
      for (int mi = 0; mi < 2; ++mi)
        af[mi] = *reinterpret_cast<const bf16x8*>(
            &As[db][wave * 32 + mi * 16 + lrow][cs]);
#pragma unroll
      for (int ni = 0; ni < 4; ++ni)
        bfv[ni] = *reinterpret_cast<const bf16x8*>(&Bs[db][ni * 16 + lrow][cs]);
#pragma unroll
      for (int mi = 0; mi < 2; ++mi)
#pragma unroll
        for (int ni = 0; ni < 4; ++ni)
          acc[mi][ni] = __builtin_amdgcn_mfma_f32_16x16x32_bf16(
              af[mi], bfv[ni], acc[mi][ni], 0, 0, 0);
    }
    lds_barrier();   // lgkm-only: prefetch loads stay in flight
    db ^= 1;
  }

  // cell update: lane owns 8 rows x 1 cell, all 4 gates in-register (g=ni)
  {
    const bf16* hc = hc0;
    bf16* hnb = hb + (((size_t)(t & 1) << 19) ^ ((size_t)1 << 19));
#pragma unroll
    for (int mi = 0; mi < 2; ++mi)
#pragma unroll
      for (int q = 0; q < 4; ++q) {
        float ig = acc[mi][0][q];
        float jg = acc[mi][1][q];
        float fg = acc[mi][2][q];
        float og = acc[mi][3][q];
        float cn = sigm(fg + 1.f) * creg[mi][q] + sigm(ig) * tanh_fast(jg);
        float hv = tanh_fast(cn) * sigm(og);
        int rr = r0 + wave * 32 + mi * 16 + hi * 4 + q;
        size_t off = ((size_t)rr << 10) + cellabs;
        float ho;
        if (t < slen[mi][q]) {
          Cb[off] = cn;          // c changes only while active
          ho = hv;
        } else {
          ho = (float)hc[off];
        }
        hnb[off] = (bf16)ho;
      }
  }
}

// ---- head ---------------------------------------------------------------
__global__ void feat_kernel(const bf16* __restrict__ hb0, const int* __restrict__ s1,
                            const int* __restrict__ s2, float* __restrict__ HC,
                            float* __restrict__ H2T) {
  int a = blockIdx.x;
  int tid = threadIdx.x;
  __shared__ float red[256];
  const bf16* h1r = hb0 + (size_t)a * HID;
  const bf16* h2r = hb0 + (size_t)(a + 256) * HID;
  float l1 = (float)s1[a] * (1.f / 128.f);
  float l2 = (float)s2[a] * (1.f / 128.f);
  float dacc = 0.f;
  for (int k = tid; k < 1025; k += 256) {
    float v1 = (k < HID) ? (float)h1r[k] : l1;
    float v2 = (k < HID) ? (float)h2r[k] : l2;
    HC[(size_t)a * HC_W + k] = v1;
    HC[(size_t)a * HC_W + 1025 + k] = v2;
    HC[(size_t)a * HC_W + 2051 + k] = v1 * v2;
    H2T[(size_t)k * 256 + a] = v2;
    float d = v1 - v2;
    dacc += d * d;
  }
  red[tid] = dacc;
  __syncthreads();
  for (int s = 128; s > 0; s >>= 1) {
    if (tid < s) red[tid] += red[tid + s];
    __syncthreads();
  }
  if (tid == 0) HC[(size_t)a * HC_W + 2050] = red[0];
}

// 8 rows/block (grid 5 x 32) — r11-proven
__global__ void t1_kernel(const float* __restrict__ HC, const float* __restrict__ Wh,
                          float* __restrict__ T1) {
  int j = blockIdx.x * 256 + threadIdx.x;
  int a0 = blockIdx.y * 8;
  __shared__ float sh[8][64];
  float acc[8];
#pragma unroll
  for (int r = 0; r < 8; ++r) acc[r] = 0.f;
  for (int kc = 0; kc < 1025; kc += 64) {
    int kn = (1025 - kc < 64) ? (1025 - kc) : 64;
    for (int idx = threadIdx.x; idx < 512; idx += 256) {
      int r = idx >> 6, kk = idx & 63;
      sh[r][kk] = (kk < kn) ? HC[(size_t)(a0 + r) * HC_W + kc + kk] : 0.f;
    }
    __syncthreads();
    if (j < 1025) {
      for (int kk = 0; kk < kn; ++kk) {
        float w = Wh[(size_t)(kc + kk) * 1025 + j];
#pragma unroll
        for (int r = 0; r < 8; ++r) acc[r] += sh[r][kk] * w;
      }
    }
    __syncthreads();
  }
  if (j < 1025) {
    for (int r = 0; r < 8; ++r) T1[(size_t)(a0 + r) * 1025 + j] = acc[r];
  }
}

__global__ void inter_kernel(const float* __restrict__ T1, const float* __restrict__ H2T,
                             float* __restrict__ HC) {
  int a0 = blockIdx.x * 8;
  int b = threadIdx.x;
  __shared__ float sT[8][1025];
  for (int idx = threadIdx.x; idx < 8 * 1025; idx += 256) {
    int r = idx / 1025, k = idx - r * 1025;
    sT[r][k] = T1[(size_t)(a0 + r) * 1025 + k];
  }
  __syncthreads();
  float acc[8];
#pragma unroll
  for (int r = 0; r < 8; ++r) acc[r] = 0.f;
  for (int k = 0; k < 1025; ++k) {
    float v = H2T[(size_t)k * 256 + b];
#pragma unroll
    for (int r = 0; r < 8; ++r) acc[r] += sT[r][k] * v;
  }
#pragma unroll
  for (int r = 0; r < 8; ++r)
    HC[(size_t)(a0 + r) * HC_W + 3076 + b] = acc[r];
}

__global__ void e1_kernel(const float* __restrict__ HC, const float* __restrict__ W1,
                          const float* __restrict__ b1, float* __restrict__ E1) {
  int a0 = blockIdx.x * 8;
  int j = blockIdx.y * 256 + threadIdx.x;
  __shared__ float sh[8][128];
  float acc[8];
#pragma unroll
  for (int r = 0; r < 8; ++r) acc[r] = 0.f;
  for (int kc = 0; kc < HC_W; kc += 128) {
    int kn = (HC_W - kc < 128) ? (HC_W - kc) : 128;
    for (int idx = threadIdx.x; idx < 1024; idx += 256) {
      int r = idx >> 7, kk = idx & 127;
      sh[r][kk] = (kk < kn) ? HC[(size_t)(a0 + r) * HC_W + kc + kk] : 0.f;
    }
    __syncthreads();
    for (int kk = 0; kk < kn; ++kk) {
      float w = W1[(size_t)(kc + kk) * 512 + j];
#pragma unroll
      for (int r = 0; r < 8; ++r) acc[r] += sh[r][kk] * w;
    }
    __syncthreads();
  }
  float bj = b1[j];
#pragma unroll
  for (int r = 0; r < 8; ++r)
    E1[(size_t)(a0 + r) * 512 + j] = fmaxf(acc[r] + bj, 0.f);
}

__global__ void out_kernel(const float* __restrict__ E1, const float* __restrict__ W2,
                           const float* __restrict__ b2, float* __restrict__ out) {
  int a = threadIdx.x;
  float a0 = 0.f, a1 = 0.f;
  const float* e = E1 + (size_t)a * 512;
  for (int k = 0; k < 512; ++k) {
    float v = e[k];
    a0 += v * W2[2 * k];
    a1 += v * W2[2 * k + 1];
  }
  out[2 * a] = a0 + b2[0];
  out[2 * a + 1] = a1 + b2[1];
}

// ---- host ---------------------------------------------------------------
extern "C" void kernel_launch(void* const* d_in, const int* in_sizes, int n_in,
                              void* d_out, int out_size, void* d_ws, size_t ws_size,
                              hipStream_t stream) {
  const int*   input1 = (const int*)d_in[0];
  const int*   input2 = (const int*)d_in[1];
  const int*   seql1  = (const int*)d_in[2];
  const int*   seql2  = (const int*)d_in[3];
  const float* emb    = (const float*)d_in[4];
  const float* lk     = (const float*)d_in[5];
  const float* lbias  = (const float*)d_in[6];
  const float* c1i    = (const float*)d_in[7];
  const float* h1i    = (const float*)d_in[8];
  const float* c2i    = (const float*)d_in[9];
  const float* h2i    = (const float*)d_in[10];
  const float* W_h    = (const float*)d_in[11];
  const float* W1     = (const float*)d_in[12];
  const float* b1     = (const float*)d_in[13];
  const float* W2     = (const float*)d_in[14];
  const float* b2     = (const float*)d_in[15];

  char* ws = (char*)d_ws;
  bf16*     WbT   = (bf16*)(ws + WBT_OFF);
  bf16*     Xb    = (bf16*)(ws + XB_OFF);
  bf16*     Hb    = (bf16*)(ws + HB_OFF);
  float*    biasp = (float*)(ws + BIASP_OFF);
  float*    Cb    = (float*)(ws + CB_OFF);
  float*    HC    = (float*)(ws + HC_OFF);   // aliases Xb (dead after lstm)
  float*    H2T   = (float*)(ws + H2T_OFF);
  float*    T1    = (float*)(ws + T1_OFF);
  float*    E1    = (float*)(ws + E1_OFF);

  pack_wbt<<<dim3(16, 1344), 256, 0, stream>>>(lk, WbT);
  pack_xb<<<dim3(512, 16), 320, 0, stream>>>(input1, input2, emb, Xb);
  pack_misc<<<2048, 256, 0, stream>>>(h1i, h2i, c1i, c2i, lbias, Hb, biasp, Cb);

  for (int t = 0; t < NSTEPS; ++t)
    lstm_step<<<256, 256, 0, stream>>>(Xb, WbT, Hb, biasp, Cb, seql1, seql2, t);

  feat_kernel<<<256, 256, 0, stream>>>(Hb, seql1, seql2, HC, H2T);
  t1_kernel<<<dim3(5, 32), 256, 0, stream>>>(HC, W_h, T1);
  inter_kernel<<<32, 256, 0, stream>>>(T1, H2T, HC);
  e1_kernel<<<dim3(32, 2), 256, 0, stream>>>(HC, W1, b1, E1);
  out_kernel<<<1, 256, 0, stream>>>(E1, W2, b2, (float*)d_out);
}

// Round 19
// 2457.667 us; speedup vs baseline: 1.9575x; 1.0878x over previous
//
#include <hip/hip_runtime.h>
#include <hip/hip_bf16.h>

typedef __bf16 bf16;
typedef __bf16 bf16x8 __attribute__((ext_vector_type(8)));
typedef float f32x4 __attribute__((ext_vector_type(4)));

#define N_ROWS   512      // rows 0..255 seq1, 256..511 seq2
#define HID      1024
#define KX       320      // EMB=300 padded to 320
#define KTOT     1344     // 320 + 1024
#define NSTEPS   128
#define EMB_D    300
#define HC_W     3332     // 1025+1025+1+1025+256

// workspace layout (bytes) — lstm phase:
#define WBT_OFF   0UL          // bf16 [4096][1344]  (packed p2 order)
#define XB_OFF    11010048UL   // bf16 [128][512][320]
#define HB_OFF    52953088UL   // bf16 [2][512][1024]
#define BIASP_OFF 55050240UL   // f32  [4096] (packed p2 order)
#define CB_OFF    55066624UL   // f32  [512][1024] cell state
// head phase (aliases Xb, dead after the recurrence):
#define HC_OFF    11010048UL   // f32 [256][3332]
#define H2T_OFF   14422016UL   // f32 [1025][256]
#define T1_OFF    15471616UL   // f32 [256][1025]
#define E1_OFF    16521216UL   // f32 [256][512]

// r18-proven: NO cooperative kernel; 128 graph-captured per-step launches.
// r19: head kernels re-gridded for occupancy + sync-free streaming K-loops
// (e1 was 365 us at 64 blocks / 3% occupancy).

__device__ __forceinline__ float sigm(float x) { return 1.f / (1.f + __expf(-x)); }
__device__ __forceinline__ float tanh_fast(float x) {
  float xc = fminf(fmaxf(x, -15.f), 15.f);
  float e = __expf(2.f * xc);
  return (e - 1.f) / (e + 1.f);
}

// LDS-only barrier (r14-proven): does not drain vmcnt.
__device__ __forceinline__ void lds_barrier() {
  asm volatile("s_waitcnt lgkmcnt(0)" ::: "memory");
  __builtin_amdgcn_sched_barrier(0);
  __builtin_amdgcn_s_barrier();
  __builtin_amdgcn_sched_barrier(0);
}

// ---- pack kernels -------------------------------------------------------
// packed order: p2 = cb*64 + g*16 + c  <->  orig col g*1024 + cb*16 + c
__global__ void pack_wbt(const float* __restrict__ lk, bf16* __restrict__ wbt) {
  int p = blockIdx.x * 256 + threadIdx.x;   // 0..4095
  int k = blockIdx.y;                        // 0..1343
  int cb = p >> 6, g = (p >> 4) & 3, c = p & 15;
  int oc = g * HID + cb * 16 + c;
  float v = 0.f;
  if (k < KX) { if (k < EMB_D) v = lk[(size_t)k * 4096 + oc]; }
  else v = lk[(size_t)(EMB_D + k - KX) * 4096 + oc];
  wbt[(size_t)p * KTOT + k] = (bf16)v;
}

// vectorized bf16x8 writes; block 320 = 8 timesteps x 40 e-groups (r11-proven)
__global__ void pack_xb(const int* __restrict__ in1, const int* __restrict__ in2,
                        const float* __restrict__ emb, bf16* __restrict__ xb) {
  int r = blockIdx.x;                        // 0..511
  int t = blockIdx.y * 8 + threadIdx.x / 40; // 0..127
  int e8 = threadIdx.x % 40;                 // 0..39 (8 elems each)
  int tok = (r < 256) ? in1[r * 128 + t] : in2[(r - 256) * 128 + t];
  const float* er = emb + (size_t)tok * EMB_D + e8 * 8;
  bf16x8 v;
  if (e8 < 37) {
#pragma unroll
    for (int i = 0; i < 8; ++i) v[i] = (bf16)er[i];
  } else {
#pragma unroll
    for (int i = 0; i < 8; ++i) {
      int e = e8 * 8 + i;
      v[i] = (e < EMB_D) ? (bf16)er[i] : (bf16)0.f;
    }
  }
  *reinterpret_cast<bf16x8*>(&xb[((size_t)t * N_ROWS + r) * KX + e8 * 8]) = v;
}

__global__ void pack_misc(const float* __restrict__ h1i, const float* __restrict__ h2i,
                          const float* __restrict__ c1i, const float* __restrict__ c2i,
                          const float* __restrict__ bias, bf16* __restrict__ hb0,
                          float* __restrict__ biasp, float* __restrict__ Cb) {
  int idx = blockIdx.x * 256 + threadIdx.x;
  if (idx < N_ROWS * HID) {
    int r = idx >> 10, k = idx & 1023;
    float v = (r < 256) ? h1i[(size_t)r * HID + k] : h2i[(size_t)(r - 256) * HID + k];
    hb0[idx] = (bf16)v;
    float cv = (r < 256) ? c1i[(size_t)r * HID + k] : c2i[(size_t)(r - 256) * HID + k];
    Cb[idx] = cv;
  }
  if (idx < 4096) {
    int cb = idx >> 6, g = (idx >> 4) & 3, c = idx & 15;
    biasp[idx] = bias[g * HID + cb * 16 + c];
  }
}

// ---- per-step LSTM kernel (r18-proven) ----------------------------------
__launch_bounds__(256, 2)
__global__ void lstm_step(const bf16* __restrict__ xb, const bf16* __restrict__ wbt,
                          bf16* __restrict__ hb, const float* __restrict__ biasp,
                          float* __restrict__ Cb, const int* __restrict__ s1,
                          const int* __restrict__ s2, int t) {
  __shared__ bf16 As[2][128][64];    // 32 KB, XOR-swizzled 16B chunks
  __shared__ bf16 Bs[2][64][64];     // 16 KB  (total 48 KB)
  const int tid = threadIdx.x;
  const int wave = tid >> 6;
  const int lane = tid & 63;
  const int lrow = lane & 15;
  const int hi = lane >> 4;        // 0..3
  const int l7 = lane & 7;
  const int bid = blockIdx.x;
  const int rb = bid >> 6;         // 0..3
  const int cb = bid & 63;         // 0..63
  const int r0 = rb * 128;

  const int cellabs = cb * 16 + lrow;    // this lane's cell column (0..1023)

  int slen[2][4];
#pragma unroll
  for (int mi = 0; mi < 2; ++mi)
#pragma unroll
    for (int q = 0; q < 4; ++q) {
      int rr = r0 + wave * 32 + mi * 16 + hi * 4 + q;
      slen[mi][q] = (rr < 256) ? s1[rr] : s2[rr - 256];
    }

  float creg[2][4];   // cell state from global
#pragma unroll
  for (int mi = 0; mi < 2; ++mi)
#pragma unroll
    for (int q = 0; q < 4; ++q) {
      int rr = r0 + wave * 32 + mi * 16 + hi * 4 + q;
      creg[mi][q] = Cb[(size_t)rr * HID + cellabs];
    }

  float bv[4];
#pragma unroll
  for (int ni = 0; ni < 4; ++ni)
    bv[ni] = biasp[cb * 64 + ni * 16 + lrow];

  const int a_r = tid >> 1, a_cb = (tid & 1) * 4;
  const int b_r = tid >> 2, b_cb = (tid & 3) * 2;

  const bf16* xt = xb + (size_t)t * N_ROWS * KX;
  const bf16* hc0 = hb + ((size_t)(t & 1) << 19);

  bf16x8 ra[4], rbv2[2];
  auto issue_loads = [&](int nkc) {
    const bf16* asrc = (nkc < 5)
        ? (xt + (size_t)(r0 + a_r) * KX + nkc * 64 + a_cb * 8)
        : (hc0 + ((size_t)(r0 + a_r) << 10) + (nkc * 64 - KX) + a_cb * 8);
#pragma unroll
    for (int q = 0; q < 4; ++q)
      ra[q] = *reinterpret_cast<const bf16x8*>(asrc + q * 8);
    const bf16* bsrc = wbt + (size_t)(cb * 64 + b_r) * KTOT + nkc * 64 + b_cb * 8;
#pragma unroll
    for (int q = 0; q < 2; ++q)
      rbv2[q] = *reinterpret_cast<const bf16x8*>(bsrc + q * 8);
  };
  auto stage_to = [&](int buf) {
#pragma unroll
    for (int q = 0; q < 4; ++q)
      *reinterpret_cast<bf16x8*>(&As[buf][a_r][((a_cb + q) ^ (a_r & 7)) << 3]) = ra[q];
#pragma unroll
    for (int q = 0; q < 2; ++q)
      *reinterpret_cast<bf16x8*>(&Bs[buf][b_r][((b_cb + q) ^ (b_r & 7)) << 3]) = rbv2[q];
  };

  issue_loads(0);
  stage_to(0);
  issue_loads(1);
  __syncthreads();
  int db = 0;

  f32x4 acc[2][4];
#pragma unroll
  for (int mi = 0; mi < 2; ++mi)
#pragma unroll
    for (int ni = 0; ni < 4; ++ni)
      acc[mi][ni] = f32x4{bv[ni], bv[ni], bv[ni], bv[ni]};

  for (int kc = 0; kc < 21; ++kc) {
    if (kc < 20) stage_to(db ^ 1);
    {
      int nkc = kc + 2;
      if (nkc <= 20) issue_loads(nkc);
    }
#pragma unroll
    for (int ks = 0; ks < 2; ++ks) {
      const int cs = (((ks << 2) | hi) ^ l7) << 3;
      bf16x8 af[2], bfv[4];
#pragma unroll
      for (int mi = 0; mi < 2; ++mi)
        af[mi] = *reinterpret_cast<const bf16x8*>(
            &As[db][wave * 32 + mi * 16 + lrow][cs]);
#pragma unroll
      for (int ni = 0; ni < 4; ++ni)
        bfv[ni] = *reinterpret_cast<const bf16x8*>(&Bs[db][ni * 16 + lrow][cs]);
#pragma unroll
      for (int mi = 0; mi < 2; ++mi)
#pragma unroll
        for (int ni = 0; ni < 4; ++ni)
          acc[mi][ni] = __builtin_amdgcn_mfma_f32_16x16x32_bf16(
              af[mi], bfv[ni], acc[mi][ni], 0, 0, 0);
    }
    lds_barrier();
    db ^= 1;
  }

  {
    const bf16* hc = hc0;
    bf16* hnb = hb + (((size_t)(t & 1) << 19) ^ ((size_t)1 << 19));
#pragma unroll
    for (int mi = 0; mi < 2; ++mi)
#pragma unroll
      for (int q = 0; q < 4; ++q) {
        float ig = acc[mi][0][q];
        float jg = acc[mi][1][q];
        float fg = acc[mi][2][q];
        float og = acc[mi][3][q];
        float cn = sigm(fg + 1.f) * creg[mi][q] + sigm(ig) * tanh_fast(jg);
        float hv = tanh_fast(cn) * sigm(og);
        int rr = r0 + wave * 32 + mi * 16 + hi * 4 + q;
        size_t off = ((size_t)rr << 10) + cellabs;
        float ho;
        if (t < slen[mi][q]) {
          Cb[off] = cn;
          ho = hv;
        } else {
          ho = (float)hc[off];
        }
        hnb[off] = (bf16)ho;
      }
  }
}

// ---- head ---------------------------------------------------------------
__global__ void feat_kernel(const bf16* __restrict__ hb0, const int* __restrict__ s1,
                            const int* __restrict__ s2, float* __restrict__ HC,
                            float* __restrict__ H2T) {
  int a = blockIdx.x;
  int tid = threadIdx.x;
  __shared__ float red[256];
  const bf16* h1r = hb0 + (size_t)a * HID;
  const bf16* h2r = hb0 + (size_t)(a + 256) * HID;
  float l1 = (float)s1[a] * (1.f / 128.f);
  float l2 = (float)s2[a] * (1.f / 128.f);
  float dacc = 0.f;
  for (int k = tid; k < 1025; k += 256) {
    float v1 = (k < HID) ? (float)h1r[k] : l1;
    float v2 = (k < HID) ? (float)h2r[k] : l2;
    HC[(size_t)a * HC_W + k] = v1;
    HC[(size_t)a * HC_W + 1025 + k] = v2;
    HC[(size_t)a * HC_W + 2051 + k] = v1 * v2;
    H2T[(size_t)k * 256 + a] = v2;
    float d = v1 - v2;
    dacc += d * d;
  }
  red[tid] = dacc;
  __syncthreads();
  for (int s = 128; s > 0; s >>= 1) {
    if (tid < s) red[tid] += red[tid + s];
    __syncthreads();
  }
  if (tid == 0) HC[(size_t)a * HC_W + 2050] = red[0];
}

// r19: 2 rows/block, sync-free streaming K loop. grid (5, 128).
__global__ void t1_kernel(const float* __restrict__ HC, const float* __restrict__ Wh,
                          float* __restrict__ T1) {
  int j = blockIdx.x * 256 + threadIdx.x;
  int a0 = blockIdx.y * 2;
  __shared__ float sh[2][1025];
  for (int idx = threadIdx.x; idx < 2050; idx += 256) {
    int r = (idx >= 1025) ? 1 : 0;
    int k = idx - r * 1025;
    sh[r][k] = HC[(size_t)(a0 + r) * HC_W + k];
  }
  __syncthreads();
  if (j < 1025) {
    float acc0 = 0.f, acc1 = 0.f;
    for (int k = 0; k < 1025; ++k) {
      float w = Wh[(size_t)k * 1025 + j];
      acc0 += sh[0][k] * w;
      acc1 += sh[1][k] * w;
    }
    T1[(size_t)a0 * 1025 + j] = acc0;
    T1[(size_t)(a0 + 1) * 1025 + j] = acc1;
  }
}

// r19: 2 rows/block, sync-free. grid 128.
__global__ void inter_kernel(const float* __restrict__ T1, const float* __restrict__ H2T,
                             float* __restrict__ HC) {
  int a0 = blockIdx.x * 2;
  int b = threadIdx.x;
  __shared__ float sT[2][1025];
  for (int idx = threadIdx.x; idx < 2050; idx += 256) {
    int r = (idx >= 1025) ? 1 : 0;
    int k = idx - r * 1025;
    sT[r][k] = T1[(size_t)(a0 + r) * 1025 + k];
  }
  __syncthreads();
  float acc0 = 0.f, acc1 = 0.f;
  for (int k = 0; k < 1025; ++k) {
    float v = H2T[(size_t)k * 256 + b];
    acc0 += sT[0][k] * v;
    acc1 += sT[1][k] * v;
  }
  HC[(size_t)a0 * HC_W + 3076 + b] = acc0;
  HC[(size_t)(a0 + 1) * HC_W + 3076 + b] = acc1;
}

// r19: 2 rows/block, sync-free streaming K loop. grid (128, 2).
__global__ void e1_kernel(const float* __restrict__ HC, const float* __restrict__ W1,
                          const float* __restrict__ b1, float* __restrict__ E1) {
  int a0 = blockIdx.x * 2;
  int j = blockIdx.y * 256 + threadIdx.x;
  __shared__ float sh[2][HC_W];   // 26,656 B
  for (int idx = threadIdx.x; idx < 2 * HC_W; idx += 256) {
    int r = (idx >= HC_W) ? 1 : 0;
    int k = idx - r * HC_W;
    sh[r][k] = HC[(size_t)(a0 + r) * HC_W + k];
  }
  __syncthreads();
  float acc0 = 0.f, acc1 = 0.f;
  for (int k = 0; k < HC_W; ++k) {
    float w = W1[(size_t)k * 512 + j];
    acc0 += sh[0][k] * w;
    acc1 += sh[1][k] * w;
  }
  float bj = b1[j];
  E1[(size_t)a0 * 512 + j] = fmaxf(acc0 + bj, 0.f);
  E1[(size_t)(a0 + 1) * 512 + j] = fmaxf(acc1 + bj, 0.f);
}

// r19: one row per block, wave-parallel partials + LDS reduce. grid 256.
__global__ void out_kernel(const float* __restrict__ E1, const float* __restrict__ W2,
                           const float* __restrict__ b2, float* __restrict__ out) {
  int a = blockIdx.x;
  int tid = threadIdx.x;
  __shared__ float red0[256], red1[256];
  float v0 = E1[(size_t)a * 512 + tid];
  float v1 = E1[(size_t)a * 512 + 256 + tid];
  float a0 = v0 * W2[2 * tid] + v1 * W2[2 * (tid + 256)];
  float a1 = v0 * W2[2 * tid + 1] + v1 * W2[2 * (tid + 256) + 1];
  red0[tid] = a0;
  red1[tid] = a1;
  __syncthreads();
  for (int s = 128; s > 0; s >>= 1) {
    if (tid < s) { red0[tid] += red0[tid + s]; red1[tid] += red1[tid + s]; }
    __syncthreads();
  }
  if (tid == 0) {
    out[2 * a] = red0[0] + b2[0];
    out[2 * a + 1] = red1[0] + b2[1];
  }
}

// ---- host ---------------------------------------------------------------
extern "C" void kernel_launch(void* const* d_in, const int* in_sizes, int n_in,
                              void* d_out, int out_size, void* d_ws, size_t ws_size,
                              hipStream_t stream) {
  const int*   input1 = (const int*)d_in[0];
  const int*   input2 = (const int*)d_in[1];
  const int*   seql1  = (const int*)d_in[2];
  const int*   seql2  = (const int*)d_in[3];
  const float* emb    = (const float*)d_in[4];
  const float* lk     = (const float*)d_in[5];
  const float* lbias  = (const float*)d_in[6];
  const float* c1i    = (const float*)d_in[7];
  const float* h1i    = (const float*)d_in[8];
  const float* c2i    = (const float*)d_in[9];
  const float* h2i    = (const float*)d_in[10];
  const float* W_h    = (const float*)d_in[11];
  const float* W1     = (const float*)d_in[12];
  const float* b1     = (const float*)d_in[13];
  const float* W2     = (const float*)d_in[14];
  const float* b2     = (const float*)d_in[15];

  char* ws = (char*)d_ws;
  bf16*     WbT   = (bf16*)(ws + WBT_OFF);
  bf16*     Xb    = (bf16*)(ws + XB_OFF);
  bf16*     Hb    = (bf16*)(ws + HB_OFF);
  float*    biasp = (float*)(ws + BIASP_OFF);
  float*    Cb    = (float*)(ws + CB_OFF);
  float*    HC    = (float*)(ws + HC_OFF);   // aliases Xb (dead after lstm)
  float*    H2T   = (float*)(ws + H2T_OFF);
  float*    T1    = (float*)(ws + T1_OFF);
  float*    E1    = (float*)(ws + E1_OFF);

  pack_wbt<<<dim3(16, 1344), 256, 0, stream>>>(lk, WbT);
  pack_xb<<<dim3(512, 16), 320, 0, stream>>>(input1, input2, emb, Xb);
  pack_misc<<<2048, 256, 0, stream>>>(h1i, h2i, c1i, c2i, lbias, Hb, biasp, Cb);

  for (int t = 0; t < NSTEPS; ++t)
    lstm_step<<<256, 256, 0, stream>>>(Xb, WbT, Hb, biasp, Cb, seql1, seql2, t);

  feat_kernel<<<256, 256, 0, stream>>>(Hb, seql1, seql2, HC, H2T);
  t1_kernel<<<dim3(5, 128), 256, 0, stream>>>(HC, W_h, T1);
  inter_kernel<<<128, 256, 0, stream>>>(T1, H2T, HC);
  e1_kernel<<<dim3(128, 2), 256, 0, stream>>>(HC, W1, b1, E1);
  out_kernel<<<256, 256, 0, stream>>>(E1, W2, b2, (float*)d_out);
}

// Round 20
// 2386.095 us; speedup vs baseline: 2.0163x; 1.0300x over previous
//
#include <hip/hip_runtime.h>
#include <hip/hip_bf16.h>

typedef __bf16 bf16;
typedef __bf16 bf16x8 __attribute__((ext_vector_type(8)));
typedef float f32x4 __attribute__((ext_vector_type(4)));

#define N_ROWS   512      // rows 0..255 seq1, 256..511 seq2
#define HID      1024
#define KX       320      // EMB=300 padded to 320
#define KTOT     1344     // 320 + 1024
#define NSTEPS   128
#define EMB_D    300
#define HC_W     3332     // 1025+1025+1+1025+256

// workspace layout (bytes) — lstm phase:
#define WBT_OFF   0UL          // bf16 [4096][1344]  (packed p2 order)
#define XB_OFF    11010048UL   // bf16 [128][512][320]
#define HB_OFF    52953088UL   // bf16 [2][512][1024]
#define BIASP_OFF 55050240UL   // f32  [4096] (packed p2 order)
#define CB_OFF    55066624UL   // f32  [512][1024] cell state
// head phase (aliases Xb, dead after the recurrence):
#define HC_OFF    11010048UL   // f32 [256][3332]
#define H2T_OFF   14422016UL   // f32 [1025][256]
#define T1A_OFF   15471616UL   // f32 [256][1025]
#define T1B_OFF   16521216UL   // f32 [256][1025]
#define E1A_OFF   17570816UL   // f32 [256][512]
#define E1B_OFF   18095104UL   // f32 [256][512]

// r18-proven: NO cooperative kernel; 128 graph-captured per-step launches.
// r20: pack_wbt LDS-transpose (was 5.5M scattered 2B stores); e1/t1 K-split
// x2 into partial buffers (more blocks/CU, shorter latency chains); inter
// 1 row/block. bias+relu folded into out_kernel.

__device__ __forceinline__ float sigm(float x) { return 1.f / (1.f + __expf(-x)); }
__device__ __forceinline__ float tanh_fast(float x) {
  float xc = fminf(fmaxf(x, -15.f), 15.f);
  float e = __expf(2.f * xc);
  return (e - 1.f) / (e + 1.f);
}

// LDS-only barrier (r14-proven): does not drain vmcnt.
__device__ __forceinline__ void lds_barrier() {
  asm volatile("s_waitcnt lgkmcnt(0)" ::: "memory");
  __builtin_amdgcn_sched_barrier(0);
  __builtin_amdgcn_s_barrier();
  __builtin_amdgcn_sched_barrier(0);
}

// ---- pack kernels -------------------------------------------------------
// packed order: p2 = cb*64 + g*16 + c  <->  orig col g*1024 + cb*16 + c
// v3: LDS-transpose tiles. block (px=cb, ky): 64 p x 64 k. Coalesced 64B
// float4 reads, contiguous 32B bf16 writes.
__global__ void pack_wbt(const float* __restrict__ lk, bf16* __restrict__ wbt) {
  __shared__ float sh[64][65];
  const int px = blockIdx.x;       // cb 0..63
  const int k0 = blockIdx.y * 64;  // 0..20 tiles (1344 = 21*64)
  const int t = threadIdx.x;
  {
    const int kk = t >> 2, g = t & 3;
    const int k = k0 + kk;
    const bool valid = (k < KX) ? (k < EMB_D) : true;
    const int src = (k < KX) ? k : (k - 20);
    const float* base = lk + (size_t)src * 4096 + g * 1024 + px * 16;
#pragma unroll
    for (int c4 = 0; c4 < 4; ++c4) {
      float4 v = valid ? *reinterpret_cast<const float4*>(base + c4 * 4)
                       : float4{0.f, 0.f, 0.f, 0.f};
      sh[kk][g * 16 + c4 * 4 + 0] = v.x;
      sh[kk][g * 16 + c4 * 4 + 1] = v.y;
      sh[kk][g * 16 + c4 * 4 + 2] = v.z;
      sh[kk][g * 16 + c4 * 4 + 3] = v.w;
    }
  }
  __syncthreads();
  {
    const int pl = t >> 2, kq = (t & 3) * 16;
    bf16 ov[16];
#pragma unroll
    for (int j = 0; j < 16; ++j) ov[j] = (bf16)sh[kq + j][pl];
    bf16* dst = wbt + (size_t)(px * 64 + pl) * KTOT + k0 + kq;
#pragma unroll
    for (int j = 0; j < 2; ++j)
      *reinterpret_cast<bf16x8*>(dst + j * 8) =
          *reinterpret_cast<const bf16x8*>(&ov[j * 8]);
  }
}

// vectorized bf16x8 writes; block 320 = 8 timesteps x 40 e-groups (r11-proven)
__global__ void pack_xb(const int* __restrict__ in1, const int* __restrict__ in2,
                        const float* __restrict__ emb, bf16* __restrict__ xb) {
  int r = blockIdx.x;                        // 0..511
  int t = blockIdx.y * 8 + threadIdx.x / 40; // 0..127
  int e8 = threadIdx.x % 40;                 // 0..39 (8 elems each)
  int tok = (r < 256) ? in1[r * 128 + t] : in2[(r - 256) * 128 + t];
  const float* er = emb + (size_t)tok * EMB_D + e8 * 8;
  bf16x8 v;
  if (e8 < 37) {
#pragma unroll
    for (int i = 0; i < 8; ++i) v[i] = (bf16)er[i];
  } else {
#pragma unroll
    for (int i = 0; i < 8; ++i) {
      int e = e8 * 8 + i;
      v[i] = (e < EMB_D) ? (bf16)er[i] : (bf16)0.f;
    }
  }
  *reinterpret_cast<bf16x8*>(&xb[((size_t)t * N_ROWS + r) * KX + e8 * 8]) = v;
}

__global__ void pack_misc(const float* __restrict__ h1i, const float* __restrict__ h2i,
                          const float* __restrict__ c1i, const float* __restrict__ c2i,
                          const float* __restrict__ bias, bf16* __restrict__ hb0,
                          float* __restrict__ biasp, float* __restrict__ Cb) {
  int idx = blockIdx.x * 256 + threadIdx.x;
  if (idx < N_ROWS * HID) {
    int r = idx >> 10, k = idx & 1023;
    float v = (r < 256) ? h1i[(size_t)r * HID + k] : h2i[(size_t)(r - 256) * HID + k];
    hb0[idx] = (bf16)v;
    float cv = (r < 256) ? c1i[(size_t)r * HID + k] : c2i[(size_t)(r - 256) * HID + k];
    Cb[idx] = cv;
  }
  if (idx < 4096) {
    int cb = idx >> 6, g = (idx >> 4) & 3, c = idx & 15;
    biasp[idx] = bias[g * HID + cb * 16 + c];
  }
}

// ---- per-step LSTM kernel (r18-proven, verbatim) ------------------------
__launch_bounds__(256, 2)
__global__ void lstm_step(const bf16* __restrict__ xb, const bf16* __restrict__ wbt,
                          bf16* __restrict__ hb, const float* __restrict__ biasp,
                          float* __restrict__ Cb, const int* __restrict__ s1,
                          const int* __restrict__ s2, int t) {
  __shared__ bf16 As[2][128][64];    // 32 KB, XOR-swizzled 16B chunks
  __shared__ bf16 Bs[2][64][64];     // 16 KB  (total 48 KB)
  const int tid = threadIdx.x;
  const int wave = tid >> 6;
  const int lane = tid & 63;
  const int lrow = lane & 15;
  const int hi = lane >> 4;        // 0..3
  const int l7 = lane & 7;
  const int bid = blockIdx.x;
  const int rb = bid >> 6;         // 0..3
  const int cb = bid & 63;         // 0..63
  const int r0 = rb * 128;

  const int cellabs = cb * 16 + lrow;    // this lane's cell column (0..1023)

  int slen[2][4];
#pragma unroll
  for (int mi = 0; mi < 2; ++mi)
#pragma unroll
    for (int q = 0; q < 4; ++q) {
      int rr = r0 + wave * 32 + mi * 16 + hi * 4 + q;
      slen[mi][q] = (rr < 256) ? s1[rr] : s2[rr - 256];
    }

  float creg[2][4];   // cell state from global
#pragma unroll
  for (int mi = 0; mi < 2; ++mi)
#pragma unroll
    for (int q = 0; q < 4; ++q) {
      int rr = r0 + wave * 32 + mi * 16 + hi * 4 + q;
      creg[mi][q] = Cb[(size_t)rr * HID + cellabs];
    }

  float bv[4];
#pragma unroll
  for (int ni = 0; ni < 4; ++ni)
    bv[ni] = biasp[cb * 64 + ni * 16 + lrow];

  const int a_r = tid >> 1, a_cb = (tid & 1) * 4;
  const int b_r = tid >> 2, b_cb = (tid & 3) * 2;

  const bf16* xt = xb + (size_t)t * N_ROWS * KX;
  const bf16* hc0 = hb + ((size_t)(t & 1) << 19);

  bf16x8 ra[4], rbv2[2];
  auto issue_loads = [&](int nkc) {
    const bf16* asrc = (nkc < 5)
        ? (xt + (size_t)(r0 + a_r) * KX + nkc * 64 + a_cb * 8)
        : (hc0 + ((size_t)(r0 + a_r) << 10) + (nkc * 64 - KX) + a_cb * 8);
#pragma unroll
    for (int q = 0; q < 4; ++q)
      ra[q] = *reinterpret_cast<const bf16x8*>(asrc + q * 8);
    const bf16* bsrc = wbt + (size_t)(cb * 64 + b_r) * KTOT + nkc * 64 + b_cb * 8;
#pragma unroll
    for (int q = 0; q < 2; ++q)
      rbv2[q] = *reinterpret_cast<const bf16x8*>(bsrc + q * 8);
  };
  auto stage_to = [&](int buf) {
#pragma unroll
    for (int q = 0; q < 4; ++q)
      *reinterpret_cast<bf16x8*>(&As[buf][a_r][((a_cb + q) ^ (a_r & 7)) << 3]) = ra[q];
#pragma unroll
    for (int q = 0; q < 2; ++q)
      *reinterpret_cast<bf16x8*>(&Bs[buf][b_r][((b_cb + q) ^ (b_r & 7)) << 3]) = rbv2[q];
  };

  issue_loads(0);
  stage_to(0);
  issue_loads(1);
  __syncthreads();
  int db = 0;

  f32x4 acc[2][4];
#pragma unroll
  for (int mi = 0; mi < 2; ++mi)
#pragma unroll
    for (int ni = 0; ni < 4; ++ni)
      acc[mi][ni] = f32x4{bv[ni], bv[ni], bv[ni], bv[ni]};

  for (int kc = 0; kc < 21; ++kc) {
    if (kc < 20) stage_to(db ^ 1);
    {
      int nkc = kc + 2;
      if (nkc <= 20) issue_loads(nkc);
    }
#pragma unroll
    for (int ks = 0; ks < 2; ++ks) {
      const int cs = (((ks << 2) | hi) ^ l7) << 3;
      bf16x8 af[2], bfv[4];
#pragma unroll
      for (int mi = 0; mi < 2; ++mi)
        af[mi] = *reinterpret_cast<const bf16x8*>(
            &As[db][wave * 32 + mi * 16 + lrow][cs]);
#pragma unroll
      for (int ni = 0; ni < 4; ++ni)
        bfv[ni] = *reinterpret_cast<const bf16x8*>(&Bs[db][ni * 16 + lrow][cs]);
#pragma unroll
      for (int mi = 0; mi < 2; ++mi)
#pragma unroll
        for (int ni = 0; ni < 4; ++ni)
          acc[mi][ni] = __builtin_amdgcn_mfma_f32_16x16x32_bf16(
              af[mi], bfv[ni], acc[mi][ni], 0, 0, 0);
    }
    lds_barrier();
    db ^= 1;
  }

  {
    const bf16* hc = hc0;
    bf16* hnb = hb + (((size_t)(t & 1) << 19) ^ ((size_t)1 << 19));
#pragma unroll
    for (int mi = 0; mi < 2; ++mi)
#pragma unroll
      for (int q = 0; q < 4; ++q) {
        float ig = acc[mi][0][q];
        float jg = acc[mi][1][q];
        float fg = acc[mi][2][q];
        float og = acc[mi][3][q];
        float cn = sigm(fg + 1.f) * creg[mi][q] + sigm(ig) * tanh_fast(jg);
        float hv = tanh_fast(cn) * sigm(og);
        int rr = r0 + wave * 32 + mi * 16 + hi * 4 + q;
        size_t off = ((size_t)rr << 10) + cellabs;
        float ho;
        if (t < slen[mi][q]) {
          Cb[off] = cn;
          ho = hv;
        } else {
          ho = (float)hc[off];
        }
        hnb[off] = (bf16)ho;
      }
  }
}

// ---- head ---------------------------------------------------------------
__global__ void feat_kernel(const bf16* __restrict__ hb0, const int* __restrict__ s1,
                            const int* __restrict__ s2, float* __restrict__ HC,
                            float* __restrict__ H2T) {
  int a = blockIdx.x;
  int tid = threadIdx.x;
  __shared__ float red[256];
  const bf16* h1r = hb0 + (size_t)a * HID;
  const bf16* h2r = hb0 + (size_t)(a + 256) * HID;
  float l1 = (float)s1[a] * (1.f / 128.f);
  float l2 = (float)s2[a] * (1.f / 128.f);
  float dacc = 0.f;
  for (int k = tid; k < 1025; k += 256) {
    float v1 = (k < HID) ? (float)h1r[k] : l1;
    float v2 = (k < HID) ? (float)h2r[k] : l2;
    HC[(size_t)a * HC_W + k] = v1;
    HC[(size_t)a * HC_W + 1025 + k] = v2;
    HC[(size_t)a * HC_W + 2051 + k] = v1 * v2;
    H2T[(size_t)k * 256 + a] = v2;
    float d = v1 - v2;
    dacc += d * d;
  }
  red[tid] = dacc;
  __syncthreads();
  for (int s = 128; s > 0; s >>= 1) {
    if (tid < s) red[tid] += red[tid + s];
    __syncthreads();
  }
  if (tid == 0) HC[(size_t)a * HC_W + 2050] = red[0];
}

// r20: 2 rows/block, K-split x2 (z): half0 k=[0,513), half1 k=[513,1025).
// grid (5, 128, 2). Partial sums to T1a / T1b.
__global__ void t1_kernel(const float* __restrict__ HC, const float* __restrict__ Wh,
                          float* __restrict__ T1a, float* __restrict__ T1b) {
  int j = blockIdx.x * 256 + threadIdx.x;
  int a0 = blockIdx.y * 2;
  int z = blockIdx.z;
  const int k0 = z ? 513 : 0;
  const int kn = z ? 512 : 513;
  __shared__ float sh[2][513];
  for (int idx = threadIdx.x; idx < 2 * kn; idx += 256) {
    int r = (idx >= kn) ? 1 : 0;
    int k = idx - r * kn;
    sh[r][k] = HC[(size_t)(a0 + r) * HC_W + k0 + k];
  }
  __syncthreads();
  if (j < 1025) {
    float acc0 = 0.f, acc1 = 0.f;
    for (int k = 0; k < kn; ++k) {
      float w = Wh[(size_t)(k0 + k) * 1025 + j];
      acc0 += sh[0][k] * w;
      acc1 += sh[1][k] * w;
    }
    float* T1 = z ? T1b : T1a;
    T1[(size_t)a0 * 1025 + j] = acc0;
    T1[(size_t)(a0 + 1) * 1025 + j] = acc1;
  }
}

// r20: 1 row/block (grid 256), reads T1a+T1b, sync-free after stage.
__global__ void inter_kernel(const float* __restrict__ T1a, const float* __restrict__ T1b,
                             const float* __restrict__ H2T, float* __restrict__ HC) {
  int a = blockIdx.x;
  int b = threadIdx.x;
  __shared__ float sT[1025];
  for (int k = threadIdx.x; k < 1025; k += 256)
    sT[k] = T1a[(size_t)a * 1025 + k] + T1b[(size_t)a * 1025 + k];
  __syncthreads();
  float acc = 0.f;
  for (int k = 0; k < 1025; ++k)
    acc += sT[k] * H2T[(size_t)k * 256 + b];
  HC[(size_t)a * HC_W + 3076 + b] = acc;
}

// r20: 2 rows/block, K-split x2 (z): halves of 1666. grid (128, 2, 2).
// Raw partial sums (no bias/relu) to E1a / E1b.
__global__ void e1_kernel(const float* __restrict__ HC, const float* __restrict__ W1,
                          float* __restrict__ E1a, float* __restrict__ E1b) {
  int a0 = blockIdx.x * 2;
  int j = blockIdx.y * 256 + threadIdx.x;
  int z = blockIdx.z;
  const int k0 = z * 1666;
  __shared__ float sh[2][1666];   // 13,328 B
  for (int idx = threadIdx.x; idx < 2 * 1666; idx += 256) {
    int r = (idx >= 1666) ? 1 : 0;
    int k = idx - r * 1666;
    sh[r][k] = HC[(size_t)(a0 + r) * HC_W + k0 + k];
  }
  __syncthreads();
  float acc0 = 0.f, acc1 = 0.f;
  for (int k = 0; k < 1666; ++k) {
    float w = W1[(size_t)(k0 + k) * 512 + j];
    acc0 += sh[0][k] * w;
    acc1 += sh[1][k] * w;
  }
  float* E1 = z ? E1b : E1a;
  E1[(size_t)a0 * 512 + j] = acc0;
  E1[(size_t)(a0 + 1) * 512 + j] = acc1;
}

// r20: bias+relu folded here: e1 = relu(E1a+E1b+b1). grid 256.
__global__ void out_kernel(const float* __restrict__ E1a, const float* __restrict__ E1b,
                           const float* __restrict__ b1, const float* __restrict__ W2,
                           const float* __restrict__ b2, float* __restrict__ out) {
  int a = blockIdx.x;
  int tid = threadIdx.x;
  __shared__ float red0[256], red1[256];
  size_t i0 = (size_t)a * 512 + tid;
  size_t i1 = i0 + 256;
  float v0 = fmaxf(E1a[i0] + E1b[i0] + b1[tid], 0.f);
  float v1 = fmaxf(E1a[i1] + E1b[i1] + b1[tid + 256], 0.f);
  float a0 = v0 * W2[2 * tid] + v1 * W2[2 * (tid + 256)];
  float a1 = v0 * W2[2 * tid + 1] + v1 * W2[2 * (tid + 256) + 1];
  red0[tid] = a0;
  red1[tid] = a1;
  __syncthreads();
  for (int s = 128; s > 0; s >>= 1) {
    if (tid < s) { red0[tid] += red0[tid + s]; red1[tid] += red1[tid + s]; }
    __syncthreads();
  }
  if (tid == 0) {
    out[2 * a] = red0[0] + b2[0];
    out[2 * a + 1] = red1[0] + b2[1];
  }
}

// ---- host ---------------------------------------------------------------
extern "C" void kernel_launch(void* const* d_in, const int* in_sizes, int n_in,
                              void* d_out, int out_size, void* d_ws, size_t ws_size,
                              hipStream_t stream) {
  const int*   input1 = (const int*)d_in[0];
  const int*   input2 = (const int*)d_in[1];
  const int*   seql1  = (const int*)d_in[2];
  const int*   seql2  = (const int*)d_in[3];
  const float* emb    = (const float*)d_in[4];
  const float* lk     = (const float*)d_in[5];
  const float* lbias  = (const float*)d_in[6];
  const float* c1i    = (const float*)d_in[7];
  const float* h1i    = (const float*)d_in[8];
  const float* c2i    = (const float*)d_in[9];
  const float* h2i    = (const float*)d_in[10];
  const float* W_h    = (const float*)d_in[11];
  const float* W1     = (const float*)d_in[12];
  const float* b1     = (const float*)d_in[13];
  const float* W2     = (const float*)d_in[14];
  const float* b2     = (const float*)d_in[15];

  char* ws = (char*)d_ws;
  bf16*     WbT   = (bf16*)(ws + WBT_OFF);
  bf16*     Xb    = (bf16*)(ws + XB_OFF);
  bf16*     Hb    = (bf16*)(ws + HB_OFF);
  float*    biasp = (float*)(ws + BIASP_OFF);
  float*    Cb    = (float*)(ws + CB_OFF);
  float*    HC    = (float*)(ws + HC_OFF);   // aliases Xb (dead after lstm)
  float*    H2T   = (float*)(ws + H2T_OFF);
  float*    T1a   = (float*)(ws + T1A_OFF);
  float*    T1b   = (float*)(ws + T1B_OFF);
  float*    E1a   = (float*)(ws + E1A_OFF);
  float*    E1b   = (float*)(ws + E1B_OFF);

  pack_wbt<<<dim3(64, 21), 256, 0, stream>>>(lk, WbT);
  pack_xb<<<dim3(512, 16), 320, 0, stream>>>(input1, input2, emb, Xb);
  pack_misc<<<2048, 256, 0, stream>>>(h1i, h2i, c1i, c2i, lbias, Hb, biasp, Cb);

  for (int t = 0; t < NSTEPS; ++t)
    lstm_step<<<256, 256, 0, stream>>>(Xb, WbT, Hb, biasp, Cb, seql1, seql2, t);

  feat_kernel<<<256, 256, 0, stream>>>(Hb, seql1, seql2, HC, H2T);
  t1_kernel<<<dim3(5, 128, 2), 256, 0, stream>>>(HC, W_h, T1a, T1b);
  inter_kernel<<<256, 256, 0, stream>>>(T1a, T1b, H2T, HC);
  e1_kernel<<<dim3(128, 2, 2), 256, 0, stream>>>(HC, W1, E1a, E1b);
  out_kernel<<<256, 256, 0, stream>>>(E1a, E1b, b1, W2, b2, (float*)d_out);
}